// Round 1
// baseline (4900.108 us; speedup 1.0000x reference)
//
#include <hip/hip_runtime.h>
#include <hip/hip_bf16.h>
#include <math.h>

#define BB 8
#define LL 2048
#define DD 128
#define HH 16
#define DQKN 64
#define DVN 256
#define MTOT (BB*LL)

#define SCALE 0.08838834764831845f  // 128^-0.5

__device__ __forceinline__ float sigmoidf_(float x){ return 1.f/(1.f+__expf(-x)); }
__device__ __forceinline__ float siluf_(float x){ return x/(1.f+__expf(-x)); }

// ---------------- bias table: bias_tab[n] = rel_bias[bucket(n)] * sqrt(DQK), n = i-j >= 0
__global__ void bias_kernel(const float* __restrict__ rel_bias, float* __restrict__ btab) {
    int n = blockIdx.x * blockDim.x + threadIdx.x;
    if (n >= LL) return;
    int bucket;
    if (n < 16) bucket = n;
    else {
        float v = logf((float)n * (1.0f/16.0f)) * (1.0f/logf(8.0f)) * 16.0f;
        bucket = 16 + (int)v;
        if (bucket > 31) bucket = 31;
    }
    btab[n] = rel_bias[bucket] * 8.0f;
}

// ---------------- EMA scan: ema[b,n,d] = sum_h red[h,d]*a_h*s_h[n], s_h[n]=r_h*s_h[n-1]+e[h,d]*x[b,n,d]
__global__ void ema_kernel(const float* __restrict__ x, const float* __restrict__ expansion,
                           const float* __restrict__ reduction, const float* __restrict__ alphas,
                           const float* __restrict__ damps, float* __restrict__ ema) {
    int b = blockIdx.x >> 1;
    int half = blockIdx.x & 1;
    int t = threadIdx.x;              // 1024 threads
    int d = half * 64 + (t >> 4);
    int h = t & 15;
    float a  = sigmoidf_(alphas[h]);
    float dm = sigmoidf_(damps[h]);
    float r = (1.f - a) * dm;
    float e = expansion[h * DD + d];
    float w = reduction[h * DD + d] * a;
    const float* xp = x + (size_t)b * LL * DD + d;
    float* op = ema + (size_t)b * LL * DD + d;
    float s = 0.f;
    #pragma unroll 4
    for (int n = 0; n < LL; ++n) {
        float xv = xp[(size_t)n * DD];
        s = fmaf(r, s, e * xv);
        float c = w * s;
        c += __shfl_xor(c, 1);
        c += __shfl_xor(c, 2);
        c += __shfl_xor(c, 4);
        c += __shfl_xor(c, 8);
        if (h == 0) op[(size_t)n * DD] = c;
    }
}

// ---------------- qk = silu(ema@W_qk + b_qk); q = qk*g0+b0; k = qk*g1+b1
__global__ void qk_kernel(const float* __restrict__ A, const float* __restrict__ W,
                          const float* __restrict__ bias, const float* __restrict__ gamma,
                          const float* __restrict__ beta, float* __restrict__ q,
                          float* __restrict__ k_out) {
    __shared__ float As[16][DD];
    int row0 = blockIdx.x * 16;
    int col = threadIdx.x;            // 64 threads
    for (int idx = threadIdx.x; idx < 16 * DD; idx += DQKN)
        As[idx >> 7][idx & 127] = A[(size_t)row0 * DD + idx];
    __syncthreads();
    float acc[16];
    #pragma unroll
    for (int r2 = 0; r2 < 16; ++r2) acc[r2] = 0.f;
    for (int k2 = 0; k2 < DD; ++k2) {
        float w = W[(size_t)k2 * DQKN + col];
        #pragma unroll
        for (int r2 = 0; r2 < 16; ++r2) acc[r2] = fmaf(As[r2][k2], w, acc[r2]);
    }
    float bb = bias[col];
    float g0 = gamma[col], g1 = gamma[DQKN + col];
    float be0 = beta[col], be1 = beta[DQKN + col];
    for (int r2 = 0; r2 < 16; ++r2) {
        float qk = siluf_(acc[r2] + bb);
        q[(size_t)(row0 + r2) * DQKN + col]     = qk * g0 + be0;
        k_out[(size_t)(row0 + r2) * DQKN + col] = qk * g1 + be1;
    }
}

// ---------------- generic rows-GEMM + activation. blockDim = N, 16 rows/block.
template<int N, int ACT>   // ACT 0=silu, 1=sigmoid
__global__ void gemm_rows(const float* __restrict__ A, const float* __restrict__ W,
                          const float* __restrict__ bias, float* __restrict__ out) {
    __shared__ float As[16][DD];
    int row0 = blockIdx.x * 16;
    int col = threadIdx.x;
    for (int idx = threadIdx.x; idx < 16 * DD; idx += N)
        As[idx >> 7][idx & 127] = A[(size_t)row0 * DD + idx];
    __syncthreads();
    float acc[16];
    #pragma unroll
    for (int r2 = 0; r2 < 16; ++r2) acc[r2] = 0.f;
    for (int k2 = 0; k2 < DD; ++k2) {
        float w = W[(size_t)k2 * N + col];
        #pragma unroll
        for (int r2 = 0; r2 < 16; ++r2) acc[r2] = fmaf(As[r2][k2], w, acc[r2]);
    }
    float bb = bias[col];
    for (int r2 = 0; r2 < 16; ++r2) {
        float p = acc[r2] + bb;
        float o = (ACT == 0) ? siluf_(p) : sigmoidf_(p);
        out[(size_t)(row0 + r2) * N + col] = o;
    }
}

// ---------------- flash attention fp32, causal, bias table. 512 thr, pairs of i-tiles.
__global__ __launch_bounds__(512) void attn_kernel(
    const float* __restrict__ q, const float* __restrict__ kk,
    const float* __restrict__ v, const float* __restrict__ btab,
    float* __restrict__ ao) {
    __shared__ float Qs[64][DQKN + 1];
    __shared__ float Ks[64][DQKN + 1];
    __shared__ float Ps[64][64 + 1];
    int b = blockIdx.y;
    int t = threadIdx.x;
    int r = t >> 3;        // 0..63 row within tile
    int c = t & 7;         // 0..7
    for (int pass = 0; pass < 2; ++pass) {
        int ti = (pass == 0) ? (int)blockIdx.x : 31 - (int)blockIdx.x;
        int i0 = ti * 64;
        __syncthreads();
        for (int idx = t; idx < 64 * DQKN; idx += 512)
            Qs[idx >> 6][idx & 63] = q[((size_t)b * LL + i0 + (idx >> 6)) * DQKN + (idx & 63)];
        __syncthreads();
        float m_run = -1e30f, l_run = 0.f;
        float acc[32];
        #pragma unroll
        for (int i2 = 0; i2 < 32; ++i2) acc[i2] = 0.f;
        int i_g = i0 + r;
        for (int tj = 0; tj <= ti; ++tj) {
            int j0 = tj * 64;
            __syncthreads();
            for (int idx = t; idx < 64 * DQKN; idx += 512)
                Ks[idx >> 6][idx & 63] = kk[((size_t)b * LL + j0 + (idx >> 6)) * DQKN + (idx & 63)];
            __syncthreads();
            float s[8];
            #pragma unroll
            for (int jj = 0; jj < 8; ++jj) s[jj] = 0.f;
            for (int k2 = 0; k2 < DQKN; ++k2) {
                float qv = Qs[r][k2];
                #pragma unroll
                for (int jj = 0; jj < 8; ++jj)
                    s[jj] = fmaf(qv, Ks[c * 8 + jj][k2], s[jj]);
            }
            float smax = -1e30f;
            #pragma unroll
            for (int jj = 0; jj < 8; ++jj) {
                int j_g = j0 + c * 8 + jj;
                if (j_g <= i_g) s[jj] = s[jj] * SCALE + btab[i_g - j_g];
                else s[jj] = -1e30f;
                smax = fmaxf(smax, s[jj]);
            }
            smax = fmaxf(smax, __shfl_xor(smax, 1));
            smax = fmaxf(smax, __shfl_xor(smax, 2));
            smax = fmaxf(smax, __shfl_xor(smax, 4));
            float m_new = fmaxf(m_run, smax);
            float alpha = __expf(m_run - m_new);
            float psum = 0.f;
            #pragma unroll
            for (int jj = 0; jj < 8; ++jj) {
                float p = __expf(s[jj] - m_new);
                Ps[r][c * 8 + jj] = p;
                psum += p;
            }
            psum += __shfl_xor(psum, 1);
            psum += __shfl_xor(psum, 2);
            psum += __shfl_xor(psum, 4);
            l_run = l_run * alpha + psum;
            m_run = m_new;
            #pragma unroll
            for (int i2 = 0; i2 < 32; ++i2) acc[i2] *= alpha;
            __syncthreads();
            const float* vp = v + ((size_t)b * LL + j0) * DVN + c * 32;
            #pragma unroll 2
            for (int j = 0; j < 64; ++j) {
                float p = Ps[r][j];
                const float* vr = vp + (size_t)j * DVN;
                #pragma unroll
                for (int dd = 0; dd < 32; dd += 4) {
                    float4 vv = *reinterpret_cast<const float4*>(vr + dd);
                    acc[dd]     = fmaf(p, vv.x, acc[dd]);
                    acc[dd + 1] = fmaf(p, vv.y, acc[dd + 1]);
                    acc[dd + 2] = fmaf(p, vv.z, acc[dd + 2]);
                    acc[dd + 3] = fmaf(p, vv.w, acc[dd + 3]);
                }
            }
        }
        float invl = 1.f / l_run;
        float* op = ao + ((size_t)b * LL + i0 + r) * DVN + c * 32;
        #pragma unroll
        for (int dd = 0; dd < 32; ++dd) op[dd] = acc[dd] * invl;
    }
}

// ---------------- final: Hh = silu(ema@Wh + (ao*reset)@Uh + bh); out = u*Hh + (1-u)*x
__global__ void final_kernel(const float* __restrict__ ema, const float* __restrict__ x,
                             const float* __restrict__ ao, const float* __restrict__ rst,
                             const float* __restrict__ upd, const float* __restrict__ Wh,
                             const float* __restrict__ Uh, const float* __restrict__ bh,
                             float* __restrict__ out) {
    __shared__ float Es[16][DD];
    __shared__ float Gs[16][DVN];
    int row0 = blockIdx.x * 16;
    int col = threadIdx.x;            // 128 threads
    for (int idx = threadIdx.x; idx < 16 * DD; idx += DD)
        Es[idx >> 7][idx & 127] = ema[(size_t)row0 * DD + idx];
    for (int idx = threadIdx.x; idx < 16 * DVN; idx += DD)
        Gs[idx >> 8][idx & 255] = ao[(size_t)row0 * DVN + idx] * rst[(size_t)row0 * DVN + idx];
    __syncthreads();
    float acc[16];
    #pragma unroll
    for (int r2 = 0; r2 < 16; ++r2) acc[r2] = 0.f;
    for (int k2 = 0; k2 < DD; ++k2) {
        float w = Wh[(size_t)k2 * DD + col];
        #pragma unroll
        for (int r2 = 0; r2 < 16; ++r2) acc[r2] = fmaf(Es[r2][k2], w, acc[r2]);
    }
    for (int k2 = 0; k2 < DVN; ++k2) {
        float w = Uh[(size_t)k2 * DD + col];
        #pragma unroll
        for (int r2 = 0; r2 < 16; ++r2) acc[r2] = fmaf(Gs[r2][k2], w, acc[r2]);
    }
    float bb = bh[col];
    for (int r2 = 0; r2 < 16; ++r2) {
        float hh = siluf_(acc[r2] + bb);
        float u = upd[(size_t)(row0 + r2) * DD + col];
        float xv = x[(size_t)(row0 + r2) * DD + col];
        out[(size_t)(row0 + r2) * DD + col] = u * hh + (1.f - u) * xv;
    }
}

extern "C" void kernel_launch(void* const* d_in, const int* in_sizes, int n_in,
                              void* d_out, int out_size, void* d_ws, size_t ws_size,
                              hipStream_t stream) {
    const float* x        = (const float*)d_in[0];
    const float* expansion= (const float*)d_in[1];
    const float* reduction= (const float*)d_in[2];
    const float* alphas   = (const float*)d_in[3];
    const float* damps    = (const float*)d_in[4];
    const float* rel_bias = (const float*)d_in[5];
    const float* W_qk     = (const float*)d_in[6];
    const float* b_qk     = (const float*)d_in[7];
    const float* gamma    = (const float*)d_in[8];
    const float* beta     = (const float*)d_in[9];
    const float* W_v      = (const float*)d_in[10];
    const float* b_v      = (const float*)d_in[11];
    const float* W_reset  = (const float*)d_in[12];
    const float* b_reset  = (const float*)d_in[13];
    const float* W_update = (const float*)d_in[14];
    const float* b_update = (const float*)d_in[15];
    const float* Wh       = (const float*)d_in[16];
    const float* Uh       = (const float*)d_in[17];
    const float* bh       = (const float*)d_in[18];
    float* out = (float*)d_out;
    float* ws = (float*)d_ws;

    float* ema = ws;
    float* q   = ema + (size_t)MTOT * DD;
    float* k   = q   + (size_t)MTOT * DQKN;
    float* v   = k   + (size_t)MTOT * DQKN;
    float* rst = v   + (size_t)MTOT * DVN;
    float* upd = rst + (size_t)MTOT * DVN;
    float* ao  = upd + (size_t)MTOT * DD;
    float* btab= ao  + (size_t)MTOT * DVN;

    bias_kernel<<<8, 256, 0, stream>>>(rel_bias, btab);
    ema_kernel<<<16, 1024, 0, stream>>>(x, expansion, reduction, alphas, damps, ema);
    qk_kernel<<<MTOT/16, DQKN, 0, stream>>>(ema, W_qk, b_qk, gamma, beta, q, k);
    gemm_rows<DVN,0><<<MTOT/16, DVN, 0, stream>>>(x,   W_v,     b_v,     v);
    gemm_rows<DVN,0><<<MTOT/16, DVN, 0, stream>>>(ema, W_reset, b_reset, rst);
    gemm_rows<DD, 1><<<MTOT/16, DD,  0, stream>>>(ema, W_update,b_update,upd);
    attn_kernel<<<dim3(16, BB), 512, 0, stream>>>(q, k, v, btab, ao);
    final_kernel<<<MTOT/16, DD, 0, stream>>>(ema, x, ao, rst, upd, Wh, Uh, bh, out);
}

// Round 2
// 1103.649 us; speedup vs baseline: 4.4399x; 4.4399x over previous
//
#include <hip/hip_runtime.h>
#include <hip/hip_bf16.h>
#include <math.h>

#define BB 8
#define LL 2048
#define DD 128
#define DQKN 64
#define DVN 256
#define MTOT (BB*LL)
#define SCALE 0.08838834764831845f  // 128^-0.5

typedef __attribute__((ext_vector_type(4))) float f32x4;
typedef __attribute__((ext_vector_type(8))) short s16x8;

__device__ __forceinline__ float sigmoidf_(float x){ return 1.f/(1.f+__expf(-x)); }
__device__ __forceinline__ float siluf_(float x){ return x/(1.f+__expf(-x)); }
__device__ __forceinline__ __hip_bfloat16 f2bf(float f){ return __float2bfloat16(f); }

// ---------------- bias table: btab[n] = rel_bias[bucket(n)] * sqrt(DQK)
__global__ void bias_kernel(const float* __restrict__ rel_bias, float* __restrict__ btab) {
    int n = blockIdx.x * blockDim.x + threadIdx.x;
    if (n >= LL) return;
    int bucket;
    if (n < 16) bucket = n;
    else {
        float v = logf((float)n * (1.0f/16.0f)) * (1.0f/logf(8.0f)) * 16.0f;
        bucket = 16 + (int)v;
        if (bucket > 31) bucket = 31;
    }
    btab[n] = rel_bias[bucket] * 8.0f;
}

// ---------------- EMA scan
__global__ void ema_kernel(const float* __restrict__ x, const float* __restrict__ expansion,
                           const float* __restrict__ reduction, const float* __restrict__ alphas,
                           const float* __restrict__ damps, float* __restrict__ ema) {
    int b = blockIdx.x >> 1;
    int half = blockIdx.x & 1;
    int t = threadIdx.x;              // 1024 threads
    int d = half * 64 + (t >> 4);
    int h = t & 15;
    float a  = sigmoidf_(alphas[h]);
    float dm = sigmoidf_(damps[h]);
    float r = (1.f - a) * dm;
    float e = expansion[h * DD + d];
    float w = reduction[h * DD + d] * a;
    const float* xp = x + (size_t)b * LL * DD + d;
    float* op = ema + (size_t)b * LL * DD + d;
    float s = 0.f;
    #pragma unroll 4
    for (int n = 0; n < LL; ++n) {
        float xv = xp[(size_t)n * DD];
        s = fmaf(r, s, e * xv);
        float c = w * s;
        c += __shfl_xor(c, 1);
        c += __shfl_xor(c, 2);
        c += __shfl_xor(c, 4);
        c += __shfl_xor(c, 8);
        if (h == 0) op[(size_t)n * DD] = c;
    }
}

// ---------------- qk = silu(ema@W_qk + b_qk) -> q,k in bf16
__global__ void qk_kernel(const float* __restrict__ A, const float* __restrict__ W,
                          const float* __restrict__ bias, const float* __restrict__ gamma,
                          const float* __restrict__ beta, __hip_bfloat16* __restrict__ q,
                          __hip_bfloat16* __restrict__ k_out) {
    __shared__ float As[16][DD];
    int row0 = blockIdx.x * 16;
    int col = threadIdx.x;            // 64 threads
    for (int idx = threadIdx.x; idx < 16 * DD; idx += DQKN)
        As[idx >> 7][idx & 127] = A[(size_t)row0 * DD + idx];
    __syncthreads();
    float acc[16];
    #pragma unroll
    for (int r2 = 0; r2 < 16; ++r2) acc[r2] = 0.f;
    for (int k4 = 0; k4 < DD/4; ++k4) {
        float w0 = W[(size_t)(k4*4+0) * DQKN + col];
        float w1 = W[(size_t)(k4*4+1) * DQKN + col];
        float w2 = W[(size_t)(k4*4+2) * DQKN + col];
        float w3 = W[(size_t)(k4*4+3) * DQKN + col];
        #pragma unroll
        for (int r2 = 0; r2 < 16; ++r2) {
            f32x4 a = *reinterpret_cast<const f32x4*>(&As[r2][k4*4]);
            acc[r2] = fmaf(a[0], w0, acc[r2]);
            acc[r2] = fmaf(a[1], w1, acc[r2]);
            acc[r2] = fmaf(a[2], w2, acc[r2]);
            acc[r2] = fmaf(a[3], w3, acc[r2]);
        }
    }
    float bb = bias[col];
    float g0 = gamma[col], g1 = gamma[DQKN + col];
    float be0 = beta[col], be1 = beta[DQKN + col];
    for (int r2 = 0; r2 < 16; ++r2) {
        float qk = siluf_(acc[r2] + bb);
        q[(size_t)(row0 + r2) * DQKN + col]     = f2bf(qk * g0 + be0);
        k_out[(size_t)(row0 + r2) * DQKN + col] = f2bf(qk * g1 + be1);
    }
}

// ---------------- generic rows-GEMM + activation. blockDim = N, 16 rows/block.
template<int N, int ACT, int OBF>   // ACT 0=silu 1=sigmoid; OBF 1 -> bf16 out
__global__ void gemm_rows(const float* __restrict__ A, const float* __restrict__ W,
                          const float* __restrict__ bias, void* __restrict__ outp) {
    __shared__ float As[16][DD];
    int row0 = blockIdx.x * 16;
    int col = threadIdx.x;
    for (int idx = threadIdx.x; idx < 16 * DD; idx += N)
        As[idx >> 7][idx & 127] = A[(size_t)row0 * DD + idx];
    __syncthreads();
    float acc[16];
    #pragma unroll
    for (int r2 = 0; r2 < 16; ++r2) acc[r2] = 0.f;
    for (int k4 = 0; k4 < DD/4; ++k4) {
        float w0 = W[(size_t)(k4*4+0) * N + col];
        float w1 = W[(size_t)(k4*4+1) * N + col];
        float w2 = W[(size_t)(k4*4+2) * N + col];
        float w3 = W[(size_t)(k4*4+3) * N + col];
        #pragma unroll
        for (int r2 = 0; r2 < 16; ++r2) {
            f32x4 a = *reinterpret_cast<const f32x4*>(&As[r2][k4*4]);
            acc[r2] = fmaf(a[0], w0, acc[r2]);
            acc[r2] = fmaf(a[1], w1, acc[r2]);
            acc[r2] = fmaf(a[2], w2, acc[r2]);
            acc[r2] = fmaf(a[3], w3, acc[r2]);
        }
    }
    float bb = bias[col];
    for (int r2 = 0; r2 < 16; ++r2) {
        float p = acc[r2] + bb;
        float o = (ACT == 0) ? siluf_(p) : sigmoidf_(p);
        if (OBF) ((__hip_bfloat16*)outp)[(size_t)(row0 + r2) * N + col] = f2bf(o);
        else     ((float*)outp)[(size_t)(row0 + r2) * N + col] = o;
    }
}

// ---------------- transpose v_bf [B*L][256] -> vT [B][256][L]
__global__ void vtrans_kernel(const __hip_bfloat16* __restrict__ vb, __hip_bfloat16* __restrict__ vT) {
    __shared__ __hip_bfloat16 tile[64][65];
    const int b = blockIdx.z;
    const int l0 = blockIdx.x * 64;
    const int n0 = blockIdx.y * 64;
    const int t = threadIdx.x;        // 256
    const int c = t & 63, r4 = t >> 6;
    #pragma unroll
    for (int p = 0; p < 16; ++p) {
        int row = p * 4 + r4;
        tile[row][c] = vb[((size_t)b * LL + l0 + row) * DVN + n0 + c];
    }
    __syncthreads();
    #pragma unroll
    for (int p = 0; p < 16; ++p) {
        int n = p * 4 + r4;
        vT[((size_t)b * DVN + n0 + n) * LL + l0 + c] = tile[c][n];
    }
}

// ---------------- MFMA flash attention, bf16 inputs, fp32 accum
__global__ __launch_bounds__(256) void attn_kernel(
    const __hip_bfloat16* __restrict__ qg, const __hip_bfloat16* __restrict__ kg,
    const __hip_bfloat16* __restrict__ vTg, const float* __restrict__ btab,
    float* __restrict__ ao) {
    __shared__ __hip_bfloat16 Ks[64 * 64];      // swizzled: byte ^= (row&7)<<4
    __shared__ __hip_bfloat16 Vs[256 * 64];     // vT tile, swizzled
    __shared__ __hip_bfloat16 Ps[4][16][72];    // per-wave P, +8 pad
    __shared__ float btabs[2048];
    const int b = blockIdx.y;
    const int ti = blockIdx.x;
    const int i0 = ti * 64;
    const int t = threadIdx.x;
    const int w = t >> 6, lane = t & 63;
    const int l16 = lane & 15, l4 = lane >> 4;
    char* KsB = (char*)Ks;
    char* VsB = (char*)Vs;

    for (int idx = t; idx < LL; idx += 256) btabs[idx] = btab[idx];

    const int irow = i0 + w * 16 + l16;
    s16x8 qf[2];
    qf[0] = *reinterpret_cast<const s16x8*>(qg + ((size_t)b * LL + irow) * DQKN + l4 * 8);
    qf[1] = *reinterpret_cast<const s16x8*>(qg + ((size_t)b * LL + irow) * DQKN + 32 + l4 * 8);

    f32x4 o[16];
    #pragma unroll
    for (int n16 = 0; n16 < 16; ++n16) o[n16] = (f32x4){0.f, 0.f, 0.f, 0.f};
    float m[4] = {-1e30f, -1e30f, -1e30f, -1e30f};
    float l[4] = {0.f, 0.f, 0.f, 0.f};

    for (int tj = 0; tj <= ti; ++tj) {
        const int j0 = tj * 64;
        __syncthreads();
        // stage K tile 64x64 (8KB)
        #pragma unroll
        for (int p = 0; p < 2; ++p) {
            int idx = p * 256 + t;
            int row = idx >> 3, c16 = idx & 7;
            uint4 d = *reinterpret_cast<const uint4*>(kg + ((size_t)b * LL + j0 + row) * DQKN + c16 * 8);
            *reinterpret_cast<uint4*>(KsB + row * 128 + ((c16 * 16) ^ ((row & 7) << 4))) = d;
        }
        // stage V^T tile 256x64 (32KB)
        #pragma unroll
        for (int p = 0; p < 8; ++p) {
            int idx = p * 256 + t;
            int n = idx >> 3, c16 = idx & 7;
            uint4 d = *reinterpret_cast<const uint4*>(vTg + ((size_t)b * DVN + n) * LL + j0 + c16 * 8);
            *reinterpret_cast<uint4*>(VsB + n * 128 + ((c16 * 16) ^ ((n & 7) << 4))) = d;
        }
        __syncthreads();
        // QK^T: S strip 16x64 per wave
        f32x4 s[4];
        #pragma unroll
        for (int t16 = 0; t16 < 4; ++t16) s[t16] = (f32x4){0.f, 0.f, 0.f, 0.f};
        #pragma unroll
        for (int c = 0; c < 2; ++c) {
            #pragma unroll
            for (int t16 = 0; t16 < 4; ++t16) {
                int j = t16 * 16 + l16;
                s16x8 kf = *reinterpret_cast<const s16x8*>(KsB + j * 128 + ((c * 64 + l4 * 16) ^ ((j & 7) << 4)));
                s[t16] = __builtin_amdgcn_mfma_f32_16x16x32_bf16(qf[c], kf, s[t16], 0, 0, 0);
            }
        }
        // scale + bias + mask, row stats
        float sv[4][4];
        float rmax[4] = {-1e30f, -1e30f, -1e30f, -1e30f};
        #pragma unroll
        for (int t16 = 0; t16 < 4; ++t16) {
            #pragma unroll
            for (int r = 0; r < 4; ++r) {
                int row = l4 * 4 + r;
                int dlt = (i0 + w * 16 + row) - (j0 + t16 * 16 + l16);
                float bv = btabs[dlt & 2047];
                float val = (dlt >= 0) ? (s[t16][r] * SCALE + bv) : -1e30f;
                sv[t16][r] = val;
                rmax[r] = fmaxf(rmax[r], val);
            }
        }
        #pragma unroll
        for (int off = 1; off < 16; off <<= 1) {
            #pragma unroll
            for (int r = 0; r < 4; ++r) rmax[r] = fmaxf(rmax[r], __shfl_xor(rmax[r], off));
        }
        float alpha[4], psum[4];
        #pragma unroll
        for (int r = 0; r < 4; ++r) {
            float mn = fmaxf(m[r], rmax[r]);
            alpha[r] = __expf(m[r] - mn);
            m[r] = mn;
            psum[r] = 0.f;
        }
        #pragma unroll
        for (int t16 = 0; t16 < 4; ++t16) {
            #pragma unroll
            for (int r = 0; r < 4; ++r) {
                float p = __expf(sv[t16][r] - m[r]);
                psum[r] += p;
                Ps[w][l4 * 4 + r][t16 * 16 + l16] = f2bf(p);
            }
        }
        #pragma unroll
        for (int off = 1; off < 16; off <<= 1) {
            #pragma unroll
            for (int r = 0; r < 4; ++r) psum[r] += __shfl_xor(psum[r], off);
        }
        #pragma unroll
        for (int r = 0; r < 4; ++r) l[r] = l[r] * alpha[r] + psum[r];
        #pragma unroll
        for (int n16 = 0; n16 < 16; ++n16) {
            #pragma unroll
            for (int r = 0; r < 4; ++r) o[n16][r] *= alpha[r];
        }
        __syncthreads();
        // PV: O strip 16x256 per wave
        #pragma unroll
        for (int c = 0; c < 2; ++c) {
            s16x8 pf = *reinterpret_cast<const s16x8*>(&Ps[w][l16][c * 32 + l4 * 8]);
            #pragma unroll
            for (int n16 = 0; n16 < 16; ++n16) {
                int n = n16 * 16 + l16;
                s16x8 vf = *reinterpret_cast<const s16x8*>(VsB + n * 128 + ((c * 64 + l4 * 16) ^ ((n & 7) << 4)));
                o[n16] = __builtin_amdgcn_mfma_f32_16x16x32_bf16(pf, vf, o[n16], 0, 0, 0);
            }
        }
    }
    float invl[4];
    #pragma unroll
    for (int r = 0; r < 4; ++r) invl[r] = 1.f / l[r];
    #pragma unroll
    for (int n16 = 0; n16 < 16; ++n16) {
        #pragma unroll
        for (int r = 0; r < 4; ++r) {
            ao[((size_t)b * LL + i0 + w * 16 + l4 * 4 + r) * DVN + n16 * 16 + l16] = o[n16][r] * invl[r];
        }
    }
}

// ---------------- final: Hh = silu(ema@Wh + (ao*reset)@Uh + bh); out = u*Hh + (1-u)*x
__global__ void final_kernel(const float* __restrict__ ema, const float* __restrict__ x,
                             const float* __restrict__ ao, const float* __restrict__ rst,
                             const float* __restrict__ upd, const float* __restrict__ Wh,
                             const float* __restrict__ Uh, const float* __restrict__ bh,
                             float* __restrict__ out) {
    __shared__ float Es[16][DD];
    __shared__ float Gs[16][DVN];
    int row0 = blockIdx.x * 16;
    int col = threadIdx.x;            // 128 threads
    for (int idx = threadIdx.x; idx < 16 * DD; idx += DD)
        Es[idx >> 7][idx & 127] = ema[(size_t)row0 * DD + idx];
    for (int idx = threadIdx.x; idx < 16 * DVN; idx += DD)
        Gs[idx >> 8][idx & 255] = ao[(size_t)row0 * DVN + idx] * rst[(size_t)row0 * DVN + idx];
    __syncthreads();
    float acc[16];
    #pragma unroll
    for (int r2 = 0; r2 < 16; ++r2) acc[r2] = 0.f;
    for (int k4 = 0; k4 < DD/4; ++k4) {
        float w0 = Wh[(size_t)(k4*4+0) * DD + col];
        float w1 = Wh[(size_t)(k4*4+1) * DD + col];
        float w2 = Wh[(size_t)(k4*4+2) * DD + col];
        float w3 = Wh[(size_t)(k4*4+3) * DD + col];
        #pragma unroll
        for (int r2 = 0; r2 < 16; ++r2) {
            f32x4 a = *reinterpret_cast<const f32x4*>(&Es[r2][k4*4]);
            acc[r2] = fmaf(a[0], w0, acc[r2]);
            acc[r2] = fmaf(a[1], w1, acc[r2]);
            acc[r2] = fmaf(a[2], w2, acc[r2]);
            acc[r2] = fmaf(a[3], w3, acc[r2]);
        }
    }
    for (int k4 = 0; k4 < DVN/4; ++k4) {
        float w0 = Uh[(size_t)(k4*4+0) * DD + col];
        float w1 = Uh[(size_t)(k4*4+1) * DD + col];
        float w2 = Uh[(size_t)(k4*4+2) * DD + col];
        float w3 = Uh[(size_t)(k4*4+3) * DD + col];
        #pragma unroll
        for (int r2 = 0; r2 < 16; ++r2) {
            f32x4 g = *reinterpret_cast<const f32x4*>(&Gs[r2][k4*4]);
            acc[r2] = fmaf(g[0], w0, acc[r2]);
            acc[r2] = fmaf(g[1], w1, acc[r2]);
            acc[r2] = fmaf(g[2], w2, acc[r2]);
            acc[r2] = fmaf(g[3], w3, acc[r2]);
        }
    }
    float bb = bh[col];
    for (int r2 = 0; r2 < 16; ++r2) {
        float hh = siluf_(acc[r2] + bb);
        float u = upd[(size_t)(row0 + r2) * DD + col];
        float xv = x[(size_t)(row0 + r2) * DD + col];
        out[(size_t)(row0 + r2) * DD + col] = u * hh + (1.f - u) * xv;
    }
}

extern "C" void kernel_launch(void* const* d_in, const int* in_sizes, int n_in,
                              void* d_out, int out_size, void* d_ws, size_t ws_size,
                              hipStream_t stream) {
    const float* x        = (const float*)d_in[0];
    const float* expansion= (const float*)d_in[1];
    const float* reduction= (const float*)d_in[2];
    const float* alphas   = (const float*)d_in[3];
    const float* damps    = (const float*)d_in[4];
    const float* rel_bias = (const float*)d_in[5];
    const float* W_qk     = (const float*)d_in[6];
    const float* b_qk     = (const float*)d_in[7];
    const float* gamma    = (const float*)d_in[8];
    const float* beta     = (const float*)d_in[9];
    const float* W_v      = (const float*)d_in[10];
    const float* b_v      = (const float*)d_in[11];
    const float* W_reset  = (const float*)d_in[12];
    const float* b_reset  = (const float*)d_in[13];
    const float* W_update = (const float*)d_in[14];
    const float* b_update = (const float*)d_in[15];
    const float* Wh       = (const float*)d_in[16];
    const float* Uh       = (const float*)d_in[17];
    const float* bh       = (const float*)d_in[18];
    float* out = (float*)d_out;

    char* base = (char*)d_ws;
    float* ema = (float*)base;                         base += (size_t)MTOT * DD * 4;
    __hip_bfloat16* qb = (__hip_bfloat16*)base;        base += (size_t)MTOT * DQKN * 2;
    __hip_bfloat16* kb = (__hip_bfloat16*)base;        base += (size_t)MTOT * DQKN * 2;
    __hip_bfloat16* vb = (__hip_bfloat16*)base;        base += (size_t)MTOT * DVN * 2;
    __hip_bfloat16* vT = (__hip_bfloat16*)base;        base += (size_t)MTOT * DVN * 2;
    float* rst = (float*)base;                         base += (size_t)MTOT * DVN * 4;
    float* upd = (float*)base;                         base += (size_t)MTOT * DD * 4;
    float* ao  = (float*)base;                         base += (size_t)MTOT * DVN * 4;
    float* btab = (float*)base;                        base += (size_t)LL * 4;

    bias_kernel<<<8, 256, 0, stream>>>(rel_bias, btab);
    ema_kernel<<<16, 1024, 0, stream>>>(x, expansion, reduction, alphas, damps, ema);
    qk_kernel<<<MTOT/16, DQKN, 0, stream>>>(ema, W_qk, b_qk, gamma, beta, qb, kb);
    gemm_rows<DVN,0,1><<<MTOT/16, DVN, 0, stream>>>(x,   W_v,     b_v,     (void*)vb);
    vtrans_kernel<<<dim3(LL/64, DVN/64, BB), 256, 0, stream>>>(vb, vT);
    gemm_rows<DVN,0,0><<<MTOT/16, DVN, 0, stream>>>(ema, W_reset, b_reset, (void*)rst);
    gemm_rows<DD, 1,0><<<MTOT/16, DD,  0, stream>>>(ema, W_update,b_update,(void*)upd);
    attn_kernel<<<dim3(LL/64, BB), 256, 0, stream>>>(qb, kb, vT, btab, ao);
    final_kernel<<<MTOT/16, DD, 0, stream>>>(ema, x, ao, rst, upd, Wh, Uh, bh, out);
}

// Round 3
// 347.650 us; speedup vs baseline: 14.0949x; 3.1746x over previous
//
#include <hip/hip_runtime.h>
#include <hip/hip_bf16.h>
#include <math.h>

#define BB 8
#define LL 2048
#define DD 128
#define DQKN 64
#define DVN 256
#define MTOT (BB*LL)
#define SCALE 0.08838834764831845f  // 128^-0.5

#define CHUNK 32
#define NCH (LL/CHUNK)   // 64

typedef __attribute__((ext_vector_type(4))) float f32x4;
typedef __attribute__((ext_vector_type(8))) short s16x8;

__device__ __forceinline__ float sigmoidf_(float x){ return 1.f/(1.f+__expf(-x)); }
__device__ __forceinline__ float siluf_(float x){ return x/(1.f+__expf(-x)); }
__device__ __forceinline__ __hip_bfloat16 f2bf(float f){ return __float2bfloat16(f); }

// ---------------- bias table: btab[n] = rel_bias[bucket(n)] * sqrt(DQK)
__global__ void bias_kernel(const float* __restrict__ rel_bias, float* __restrict__ btab) {
    int n = blockIdx.x * blockDim.x + threadIdx.x;
    if (n >= LL) return;
    int bucket;
    if (n < 16) bucket = n;
    else {
        float v = logf((float)n * (1.0f/16.0f)) * (1.0f/logf(8.0f)) * 16.0f;
        bucket = 16 + (int)v;
        if (bucket > 31) bucket = 31;
    }
    btab[n] = rel_bias[bucket] * 8.0f;
}

// ---------------- EMA chunked scan. u_h[n] = r_h*u_h[n-1] + x[n]; ema = sum_h we[h,d]*u_h
// Pass A: local scan per chunk (zero init), write end states sl[B][NCH][16][D]
__global__ __launch_bounds__(256) void ema_scanA(const float* __restrict__ x,
                                                 const float* __restrict__ alphas,
                                                 const float* __restrict__ damps,
                                                 float* __restrict__ sl) {
    int tid = blockIdx.x * 256 + threadIdx.x;   // 65536
    int d = tid & 127;
    int c = (tid >> 7) & (NCH - 1);
    int b = tid >> 13;
    float u[16], r[16];
    #pragma unroll
    for (int h = 0; h < 16; ++h) {
        float a = sigmoidf_(alphas[h]);
        r[h] = (1.f - a) * sigmoidf_(damps[h]);
        u[h] = 0.f;
    }
    const float* xp = x + ((size_t)b * LL + c * CHUNK) * DD + d;
    #pragma unroll 4
    for (int i = 0; i < CHUNK; ++i) {
        float xv = xp[(size_t)i * DD];
        #pragma unroll
        for (int h = 0; h < 16; ++h) u[h] = fmaf(r[h], u[h], xv);
    }
    float* slp = sl + ((size_t)b * NCH + c) * 16 * DD + d;
    #pragma unroll
    for (int h = 0; h < 16; ++h) slp[(size_t)h * DD] = u[h];
}

// Pass B: propagate carries across chunks. carry[b][c][h][d] = state before chunk c.
__global__ __launch_bounds__(256) void ema_scanB(const float* __restrict__ alphas,
                                                 const float* __restrict__ damps,
                                                 const float* __restrict__ sl,
                                                 float* __restrict__ carry) {
    int tid = blockIdx.x * 256 + threadIdx.x;   // 16384
    int d = tid & 127;
    int h = (tid >> 7) & 15;
    int b = tid >> 11;
    float a = sigmoidf_(alphas[h]);
    float r = (1.f - a) * sigmoidf_(damps[h]);
    float rC = r;
    #pragma unroll
    for (int q = 0; q < 5; ++q) rC *= rC;       // r^32
    const float* slp = sl + ((size_t)b * NCH * 16 + h) * DD + d;
    float* cp = carry + ((size_t)b * NCH * 16 + h) * DD + d;
    float u = 0.f;
    for (int c = 0; c < NCH; ++c) {
        cp[(size_t)c * 16 * DD] = u;
        u = slp[(size_t)c * 16 * DD] + rC * u;
    }
}

// Pass C: scan with carried init state, emit ema.
__global__ __launch_bounds__(256) void ema_scanC(const float* __restrict__ x,
                                                 const float* __restrict__ expansion,
                                                 const float* __restrict__ reduction,
                                                 const float* __restrict__ alphas,
                                                 const float* __restrict__ damps,
                                                 const float* __restrict__ carry,
                                                 float* __restrict__ ema) {
    int tid = blockIdx.x * 256 + threadIdx.x;   // 65536
    int d = tid & 127;
    int c = (tid >> 7) & (NCH - 1);
    int b = tid >> 13;
    float u[16], r[16], we[16];
    #pragma unroll
    for (int h = 0; h < 16; ++h) {
        float a = sigmoidf_(alphas[h]);
        r[h] = (1.f - a) * sigmoidf_(damps[h]);
        we[h] = reduction[h * DD + d] * a * expansion[h * DD + d];
        u[h] = carry[((size_t)b * NCH + c) * 16 * DD + (size_t)h * DD + d];
    }
    const float* xp = x + ((size_t)b * LL + c * CHUNK) * DD + d;
    float* op = ema + ((size_t)b * LL + c * CHUNK) * DD + d;
    #pragma unroll 4
    for (int i = 0; i < CHUNK; ++i) {
        float xv = xp[(size_t)i * DD];
        float acc = 0.f;
        #pragma unroll
        for (int h = 0; h < 16; ++h) {
            u[h] = fmaf(r[h], u[h], xv);
            acc = fmaf(we[h], u[h], acc);
        }
        op[(size_t)i * DD] = acc;
    }
}

// ---------------- qk = silu(ema@W_qk + b_qk) -> q,k in bf16
__global__ void qk_kernel(const float* __restrict__ A, const float* __restrict__ W,
                          const float* __restrict__ bias, const float* __restrict__ gamma,
                          const float* __restrict__ beta, __hip_bfloat16* __restrict__ q,
                          __hip_bfloat16* __restrict__ k_out) {
    __shared__ float As[16][DD];
    int row0 = blockIdx.x * 16;
    int col = threadIdx.x;            // 64 threads
    for (int idx = threadIdx.x; idx < 16 * DD; idx += DQKN)
        As[idx >> 7][idx & 127] = A[(size_t)row0 * DD + idx];
    __syncthreads();
    float acc[16];
    #pragma unroll
    for (int r2 = 0; r2 < 16; ++r2) acc[r2] = 0.f;
    for (int k4 = 0; k4 < DD/4; ++k4) {
        float w0 = W[(size_t)(k4*4+0) * DQKN + col];
        float w1 = W[(size_t)(k4*4+1) * DQKN + col];
        float w2 = W[(size_t)(k4*4+2) * DQKN + col];
        float w3 = W[(size_t)(k4*4+3) * DQKN + col];
        #pragma unroll
        for (int r2 = 0; r2 < 16; ++r2) {
            f32x4 a = *reinterpret_cast<const f32x4*>(&As[r2][k4*4]);
            acc[r2] = fmaf(a[0], w0, acc[r2]);
            acc[r2] = fmaf(a[1], w1, acc[r2]);
            acc[r2] = fmaf(a[2], w2, acc[r2]);
            acc[r2] = fmaf(a[3], w3, acc[r2]);
        }
    }
    float bb = bias[col];
    float g0 = gamma[col], g1 = gamma[DQKN + col];
    float be0 = beta[col], be1 = beta[DQKN + col];
    for (int r2 = 0; r2 < 16; ++r2) {
        float qk = siluf_(acc[r2] + bb);
        q[(size_t)(row0 + r2) * DQKN + col]     = f2bf(qk * g0 + be0);
        k_out[(size_t)(row0 + r2) * DQKN + col] = f2bf(qk * g1 + be1);
    }
}

// ---------------- generic rows-GEMM + activation. blockDim = N, 16 rows/block.
template<int N, int ACT, int OBF>   // ACT 0=silu 1=sigmoid; OBF 1 -> bf16 out
__global__ void gemm_rows(const float* __restrict__ A, const float* __restrict__ W,
                          const float* __restrict__ bias, void* __restrict__ outp) {
    __shared__ float As[16][DD];
    int row0 = blockIdx.x * 16;
    int col = threadIdx.x;
    for (int idx = threadIdx.x; idx < 16 * DD; idx += N)
        As[idx >> 7][idx & 127] = A[(size_t)row0 * DD + idx];
    __syncthreads();
    float acc[16];
    #pragma unroll
    for (int r2 = 0; r2 < 16; ++r2) acc[r2] = 0.f;
    for (int k4 = 0; k4 < DD/4; ++k4) {
        float w0 = W[(size_t)(k4*4+0) * N + col];
        float w1 = W[(size_t)(k4*4+1) * N + col];
        float w2 = W[(size_t)(k4*4+2) * N + col];
        float w3 = W[(size_t)(k4*4+3) * N + col];
        #pragma unroll
        for (int r2 = 0; r2 < 16; ++r2) {
            f32x4 a = *reinterpret_cast<const f32x4*>(&As[r2][k4*4]);
            acc[r2] = fmaf(a[0], w0, acc[r2]);
            acc[r2] = fmaf(a[1], w1, acc[r2]);
            acc[r2] = fmaf(a[2], w2, acc[r2]);
            acc[r2] = fmaf(a[3], w3, acc[r2]);
        }
    }
    float bb = bias[col];
    for (int r2 = 0; r2 < 16; ++r2) {
        float p = acc[r2] + bb;
        float o = (ACT == 0) ? siluf_(p) : sigmoidf_(p);
        if (OBF) ((__hip_bfloat16*)outp)[(size_t)(row0 + r2) * N + col] = f2bf(o);
        else     ((float*)outp)[(size_t)(row0 + r2) * N + col] = o;
    }
}

// ---------------- transpose v_bf [B*L][256] -> vT [B][256][L]
__global__ void vtrans_kernel(const __hip_bfloat16* __restrict__ vb, __hip_bfloat16* __restrict__ vT) {
    __shared__ __hip_bfloat16 tile[64][65];
    const int b = blockIdx.z;
    const int l0 = blockIdx.x * 64;
    const int n0 = blockIdx.y * 64;
    const int t = threadIdx.x;        // 256
    const int c = t & 63, r4 = t >> 6;
    #pragma unroll
    for (int p = 0; p < 16; ++p) {
        int row = p * 4 + r4;
        tile[row][c] = vb[((size_t)b * LL + l0 + row) * DVN + n0 + c];
    }
    __syncthreads();
    #pragma unroll
    for (int p = 0; p < 16; ++p) {
        int n = p * 4 + r4;
        vT[((size_t)b * DVN + n0 + n) * LL + l0 + c] = tile[c][n];
    }
}

// ---------------- MFMA flash attention, bf16 inputs, fp32 accum
__global__ __launch_bounds__(256) void attn_kernel(
    const __hip_bfloat16* __restrict__ qg, const __hip_bfloat16* __restrict__ kg,
    const __hip_bfloat16* __restrict__ vTg, const float* __restrict__ btab,
    float* __restrict__ ao) {
    __shared__ __hip_bfloat16 Ks[64 * 64];      // swizzled: byte ^= (row&7)<<4
    __shared__ __hip_bfloat16 Vs[256 * 64];     // vT tile, swizzled
    __shared__ __hip_bfloat16 Ps[4][16][72];    // per-wave P, +8 pad
    __shared__ float btabs[2048];
    const int b = blockIdx.y;
    const int ti = blockIdx.x;
    const int i0 = ti * 64;
    const int t = threadIdx.x;
    const int w = t >> 6, lane = t & 63;
    const int l16 = lane & 15, l4 = lane >> 4;
    char* KsB = (char*)Ks;
    char* VsB = (char*)Vs;

    for (int idx = t; idx < LL; idx += 256) btabs[idx] = btab[idx];

    const int irow = i0 + w * 16 + l16;
    s16x8 qf[2];
    qf[0] = *reinterpret_cast<const s16x8*>(qg + ((size_t)b * LL + irow) * DQKN + l4 * 8);
    qf[1] = *reinterpret_cast<const s16x8*>(qg + ((size_t)b * LL + irow) * DQKN + 32 + l4 * 8);

    f32x4 o[16];
    #pragma unroll
    for (int n16 = 0; n16 < 16; ++n16) o[n16] = (f32x4){0.f, 0.f, 0.f, 0.f};
    float m[4] = {-1e30f, -1e30f, -1e30f, -1e30f};
    float l[4] = {0.f, 0.f, 0.f, 0.f};

    for (int tj = 0; tj <= ti; ++tj) {
        const int j0 = tj * 64;
        __syncthreads();
        // stage K tile 64x64 (8KB)
        #pragma unroll
        for (int p = 0; p < 2; ++p) {
            int idx = p * 256 + t;
            int row = idx >> 3, c16 = idx & 7;
            uint4 d = *reinterpret_cast<const uint4*>(kg + ((size_t)b * LL + j0 + row) * DQKN + c16 * 8);
            *reinterpret_cast<uint4*>(KsB + row * 128 + ((c16 * 16) ^ ((row & 7) << 4))) = d;
        }
        // stage V^T tile 256x64 (32KB)
        #pragma unroll
        for (int p = 0; p < 8; ++p) {
            int idx = p * 256 + t;
            int n = idx >> 3, c16 = idx & 7;
            uint4 d = *reinterpret_cast<const uint4*>(vTg + ((size_t)b * DVN + n) * LL + j0 + c16 * 8);
            *reinterpret_cast<uint4*>(VsB + n * 128 + ((c16 * 16) ^ ((n & 7) << 4))) = d;
        }
        __syncthreads();
        // QK^T: S strip 16x64 per wave
        f32x4 s[4];
        #pragma unroll
        for (int t16 = 0; t16 < 4; ++t16) s[t16] = (f32x4){0.f, 0.f, 0.f, 0.f};
        #pragma unroll
        for (int c = 0; c < 2; ++c) {
            #pragma unroll
            for (int t16 = 0; t16 < 4; ++t16) {
                int j = t16 * 16 + l16;
                s16x8 kf = *reinterpret_cast<const s16x8*>(KsB + j * 128 + ((c * 64 + l4 * 16) ^ ((j & 7) << 4)));
                s[t16] = __builtin_amdgcn_mfma_f32_16x16x32_bf16(qf[c], kf, s[t16], 0, 0, 0);
            }
        }
        // scale + bias + mask, row stats
        float sv[4][4];
        float rmax[4] = {-1e30f, -1e30f, -1e30f, -1e30f};
        #pragma unroll
        for (int t16 = 0; t16 < 4; ++t16) {
            #pragma unroll
            for (int r = 0; r < 4; ++r) {
                int row = l4 * 4 + r;
                int dlt = (i0 + w * 16 + row) - (j0 + t16 * 16 + l16);
                float bv = btabs[dlt & 2047];
                float val = (dlt >= 0) ? (s[t16][r] * SCALE + bv) : -1e30f;
                sv[t16][r] = val;
                rmax[r] = fmaxf(rmax[r], val);
            }
        }
        #pragma unroll
        for (int off = 1; off < 16; off <<= 1) {
            #pragma unroll
            for (int r = 0; r < 4; ++r) rmax[r] = fmaxf(rmax[r], __shfl_xor(rmax[r], off));
        }
        float alpha[4], psum[4];
        #pragma unroll
        for (int r = 0; r < 4; ++r) {
            float mn = fmaxf(m[r], rmax[r]);
            alpha[r] = __expf(m[r] - mn);
            m[r] = mn;
            psum[r] = 0.f;
        }
        #pragma unroll
        for (int t16 = 0; t16 < 4; ++t16) {
            #pragma unroll
            for (int r = 0; r < 4; ++r) {
                float p = __expf(sv[t16][r] - m[r]);
                psum[r] += p;
                Ps[w][l4 * 4 + r][t16 * 16 + l16] = f2bf(p);
            }
        }
        #pragma unroll
        for (int off = 1; off < 16; off <<= 1) {
            #pragma unroll
            for (int r = 0; r < 4; ++r) psum[r] += __shfl_xor(psum[r], off);
        }
        #pragma unroll
        for (int r = 0; r < 4; ++r) l[r] = l[r] * alpha[r] + psum[r];
        #pragma unroll
        for (int n16 = 0; n16 < 16; ++n16) {
            #pragma unroll
            for (int r = 0; r < 4; ++r) o[n16][r] *= alpha[r];
        }
        __syncthreads();
        // PV: O strip 16x256 per wave
        #pragma unroll
        for (int c = 0; c < 2; ++c) {
            s16x8 pf = *reinterpret_cast<const s16x8*>(&Ps[w][l16][c * 32 + l4 * 8]);
            #pragma unroll
            for (int n16 = 0; n16 < 16; ++n16) {
                int n = n16 * 16 + l16;
                s16x8 vf = *reinterpret_cast<const s16x8*>(VsB + n * 128 + ((c * 64 + l4 * 16) ^ ((n & 7) << 4)));
                o[n16] = __builtin_amdgcn_mfma_f32_16x16x32_bf16(pf, vf, o[n16], 0, 0, 0);
            }
        }
    }
    float invl[4];
    #pragma unroll
    for (int r = 0; r < 4; ++r) invl[r] = 1.f / l[r];
    #pragma unroll
    for (int n16 = 0; n16 < 16; ++n16) {
        #pragma unroll
        for (int r = 0; r < 4; ++r) {
            ao[((size_t)b * LL + i0 + w * 16 + l4 * 4 + r) * DVN + n16 * 16 + l16] = o[n16][r] * invl[r];
        }
    }
}

// ---------------- final: Hh = silu(ema@Wh + (ao*reset)@Uh + bh); out = u*Hh + (1-u)*x
__global__ void final_kernel(const float* __restrict__ ema, const float* __restrict__ x,
                             const float* __restrict__ ao, const float* __restrict__ rst,
                             const float* __restrict__ upd, const float* __restrict__ Wh,
                             const float* __restrict__ Uh, const float* __restrict__ bh,
                             float* __restrict__ out) {
    __shared__ float Es[16][DD];
    __shared__ float Gs[16][DVN];
    int row0 = blockIdx.x * 16;
    int col = threadIdx.x;            // 128 threads
    for (int idx = threadIdx.x; idx < 16 * DD; idx += DD)
        Es[idx >> 7][idx & 127] = ema[(size_t)row0 * DD + idx];
    for (int idx = threadIdx.x; idx < 16 * DVN; idx += DD)
        Gs[idx >> 8][idx & 255] = ao[(size_t)row0 * DVN + idx] * rst[(size_t)row0 * DVN + idx];
    __syncthreads();
    float acc[16];
    #pragma unroll
    for (int r2 = 0; r2 < 16; ++r2) acc[r2] = 0.f;
    for (int k4 = 0; k4 < DD/4; ++k4) {
        float w0 = Wh[(size_t)(k4*4+0) * DD + col];
        float w1 = Wh[(size_t)(k4*4+1) * DD + col];
        float w2 = Wh[(size_t)(k4*4+2) * DD + col];
        float w3 = Wh[(size_t)(k4*4+3) * DD + col];
        #pragma unroll
        for (int r2 = 0; r2 < 16; ++r2) {
            f32x4 a = *reinterpret_cast<const f32x4*>(&Es[r2][k4*4]);
            acc[r2] = fmaf(a[0], w0, acc[r2]);
            acc[r2] = fmaf(a[1], w1, acc[r2]);
            acc[r2] = fmaf(a[2], w2, acc[r2]);
            acc[r2] = fmaf(a[3], w3, acc[r2]);
        }
    }
    for (int k4 = 0; k4 < DVN/4; ++k4) {
        float w0 = Uh[(size_t)(k4*4+0) * DD + col];
        float w1 = Uh[(size_t)(k4*4+1) * DD + col];
        float w2 = Uh[(size_t)(k4*4+2) * DD + col];
        float w3 = Uh[(size_t)(k4*4+3) * DD + col];
        #pragma unroll
        for (int r2 = 0; r2 < 16; ++r2) {
            f32x4 g = *reinterpret_cast<const f32x4*>(&Gs[r2][k4*4]);
            acc[r2] = fmaf(g[0], w0, acc[r2]);
            acc[r2] = fmaf(g[1], w1, acc[r2]);
            acc[r2] = fmaf(g[2], w2, acc[r2]);
            acc[r2] = fmaf(g[3], w3, acc[r2]);
        }
    }
    float bb = bh[col];
    for (int r2 = 0; r2 < 16; ++r2) {
        float hh = siluf_(acc[r2] + bb);
        float u = upd[(size_t)(row0 + r2) * DD + col];
        float xv = x[(size_t)(row0 + r2) * DD + col];
        out[(size_t)(row0 + r2) * DD + col] = u * hh + (1.f - u) * xv;
    }
}

extern "C" void kernel_launch(void* const* d_in, const int* in_sizes, int n_in,
                              void* d_out, int out_size, void* d_ws, size_t ws_size,
                              hipStream_t stream) {
    const float* x        = (const float*)d_in[0];
    const float* expansion= (const float*)d_in[1];
    const float* reduction= (const float*)d_in[2];
    const float* alphas   = (const float*)d_in[3];
    const float* damps    = (const float*)d_in[4];
    const float* rel_bias = (const float*)d_in[5];
    const float* W_qk     = (const float*)d_in[6];
    const float* b_qk     = (const float*)d_in[7];
    const float* gamma    = (const float*)d_in[8];
    const float* beta     = (const float*)d_in[9];
    const float* W_v      = (const float*)d_in[10];
    const float* b_v      = (const float*)d_in[11];
    const float* W_reset  = (const float*)d_in[12];
    const float* b_reset  = (const float*)d_in[13];
    const float* W_update = (const float*)d_in[14];
    const float* b_update = (const float*)d_in[15];
    const float* Wh       = (const float*)d_in[16];
    const float* Uh       = (const float*)d_in[17];
    const float* bh       = (const float*)d_in[18];
    float* out = (float*)d_out;

    char* base = (char*)d_ws;
    float* ema = (float*)base;                         base += (size_t)MTOT * DD * 4;
    __hip_bfloat16* qb = (__hip_bfloat16*)base;        base += (size_t)MTOT * DQKN * 2;
    __hip_bfloat16* kb = (__hip_bfloat16*)base;        base += (size_t)MTOT * DQKN * 2;
    __hip_bfloat16* vb = (__hip_bfloat16*)base;        base += (size_t)MTOT * DVN * 2;
    __hip_bfloat16* vT = (__hip_bfloat16*)base;        base += (size_t)MTOT * DVN * 2;
    float* rst = (float*)base;                         base += (size_t)MTOT * DVN * 4;
    float* upd = (float*)base;                         base += (size_t)MTOT * DD * 4;
    float* ao  = (float*)base;                         base += (size_t)MTOT * DVN * 4;
    float* btab = (float*)base;                        base += (size_t)LL * 4;
    float* sl   = (float*)base;                        base += (size_t)BB * NCH * 16 * DD * 4;
    float* carry= (float*)base;                        base += (size_t)BB * NCH * 16 * DD * 4;

    bias_kernel<<<8, 256, 0, stream>>>(rel_bias, btab);
    ema_scanA<<<BB * NCH * DD / 256, 256, 0, stream>>>(x, alphas, damps, sl);
    ema_scanB<<<BB * 16 * DD / 256, 256, 0, stream>>>(alphas, damps, sl, carry);
    ema_scanC<<<BB * NCH * DD / 256, 256, 0, stream>>>(x, expansion, reduction, alphas, damps, carry, ema);
    qk_kernel<<<MTOT/16, DQKN, 0, stream>>>(ema, W_qk, b_qk, gamma, beta, qb, kb);
    gemm_rows<DVN,0,1><<<MTOT/16, DVN, 0, stream>>>(x,   W_v,     b_v,     (void*)vb);
    vtrans_kernel<<<dim3(LL/64, DVN/64, BB), 256, 0, stream>>>(vb, vT);
    gemm_rows<DVN,0,0><<<MTOT/16, DVN, 0, stream>>>(ema, W_reset, b_reset, (void*)rst);
    gemm_rows<DD, 1,0><<<MTOT/16, DD,  0, stream>>>(ema, W_update,b_update,(void*)upd);
    attn_kernel<<<dim3(LL/64, BB), 256, 0, stream>>>(qb, kb, vT, btab, ao);
    final_kernel<<<MTOT/16, DD, 0, stream>>>(ema, x, ao, rst, upd, Wh, Uh, bh, out);
}

// Round 4
// 288.167 us; speedup vs baseline: 17.0044x; 1.2064x over previous
//
#include <hip/hip_runtime.h>
#include <hip/hip_bf16.h>
#include <math.h>

#define BB 8
#define LL 2048
#define DD 128
#define DQKN 64
#define DVN 256
#define MTOT (BB*LL)
#define SCALE 0.08838834764831845f  // 128^-0.5

#define CHUNK 32
#define NCH (LL/CHUNK)   // 64

typedef __attribute__((ext_vector_type(4))) float f32x4;
typedef __attribute__((ext_vector_type(8))) short s16x8;

__device__ __forceinline__ float sigmoidf_(float x){ return 1.f/(1.f+__expf(-x)); }
__device__ __forceinline__ float siluf_(float x){ return x/(1.f+__expf(-x)); }
__device__ __forceinline__ __hip_bfloat16 f2bf(float f){ return __float2bfloat16(f); }
__device__ __forceinline__ ushort f2bfu(float f){ __hip_bfloat16 h = __float2bfloat16(f); return *(const ushort*)&h; }
__device__ __forceinline__ float bf2f(ushort u){ union{unsigned i; float f;} v; v.i = ((unsigned)u)<<16; return v.f; }

// ---------------- bias table: btab[n] = rel_bias[bucket(n)] * sqrt(DQK)
__global__ void bias_kernel(const float* __restrict__ rel_bias, float* __restrict__ btab) {
    int n = blockIdx.x * blockDim.x + threadIdx.x;
    if (n >= LL) return;
    int bucket;
    if (n < 16) bucket = n;
    else {
        float v = logf((float)n * (1.0f/16.0f)) * (1.0f/logf(8.0f)) * 16.0f;
        bucket = 16 + (int)v;
        if (bucket > 31) bucket = 31;
    }
    btab[n] = rel_bias[bucket] * 8.0f;
}

// ---------------- pack W[K][N] fp32 -> bf16 MFMA B-fragments
// Wp[((n16*(K/32)+k32)*64 + lane)*8 + j] = W[k32*32 + (lane/16)*8 + j][n16*16 + lane%16]
template<int K, int N>
__global__ void pack_w(const float* __restrict__ W, __hip_bfloat16* __restrict__ Wp) {
    int blk = blockIdx.x;            // n16*(K/32) + k32
    int l = threadIdx.x;             // 64
    int k32 = blk % (K/32), n16 = blk / (K/32);
    int col = n16*16 + (l & 15);
    int krow = k32*32 + (l >> 4)*8;
    ushort tmp[8];
    #pragma unroll
    for (int j = 0; j < 8; ++j) tmp[j] = f2bfu(W[(size_t)(krow + j)*N + col]);
    *reinterpret_cast<uint4*>(Wp + ((size_t)blk*64 + l)*8) = *reinterpret_cast<uint4*>(tmp);
}

// ---------------- EMA chunked scan
__global__ __launch_bounds__(256) void ema_scanA(const float* __restrict__ x,
                                                 const float* __restrict__ alphas,
                                                 const float* __restrict__ damps,
                                                 float* __restrict__ sl) {
    int tid = blockIdx.x * 256 + threadIdx.x;   // 65536
    int d = tid & 127;
    int c = (tid >> 7) & (NCH - 1);
    int b = tid >> 13;
    float u[16], r[16];
    #pragma unroll
    for (int h = 0; h < 16; ++h) {
        float a = sigmoidf_(alphas[h]);
        r[h] = (1.f - a) * sigmoidf_(damps[h]);
        u[h] = 0.f;
    }
    const float* xp = x + ((size_t)b * LL + c * CHUNK) * DD + d;
    #pragma unroll 4
    for (int i = 0; i < CHUNK; ++i) {
        float xv = xp[(size_t)i * DD];
        #pragma unroll
        for (int h = 0; h < 16; ++h) u[h] = fmaf(r[h], u[h], xv);
    }
    float* slp = sl + ((size_t)b * NCH + c) * 16 * DD + d;
    #pragma unroll
    for (int h = 0; h < 16; ++h) slp[(size_t)h * DD] = u[h];
}

__global__ __launch_bounds__(256) void ema_scanB(const float* __restrict__ alphas,
                                                 const float* __restrict__ damps,
                                                 const float* __restrict__ sl,
                                                 float* __restrict__ carry) {
    int tid = blockIdx.x * 256 + threadIdx.x;   // 16384
    int d = tid & 127;
    int h = (tid >> 7) & 15;
    int b = tid >> 11;
    float a = sigmoidf_(alphas[h]);
    float r = (1.f - a) * sigmoidf_(damps[h]);
    float rC = r;
    #pragma unroll
    for (int q = 0; q < 5; ++q) rC *= rC;       // r^32
    const float* slp = sl + ((size_t)b * NCH * 16 + h) * DD + d;
    float* cp = carry + ((size_t)b * NCH * 16 + h) * DD + d;
    float u = 0.f;
    for (int c = 0; c < NCH; ++c) {
        cp[(size_t)c * 16 * DD] = u;
        u = slp[(size_t)c * 16 * DD] + rC * u;
    }
}

// Pass C: scan with carry, emit ema (bf16) and x (bf16)
__global__ __launch_bounds__(256) void ema_scanC(const float* __restrict__ x,
                                                 const float* __restrict__ expansion,
                                                 const float* __restrict__ reduction,
                                                 const float* __restrict__ alphas,
                                                 const float* __restrict__ damps,
                                                 const float* __restrict__ carry,
                                                 __hip_bfloat16* __restrict__ emab,
                                                 __hip_bfloat16* __restrict__ xb) {
    int tid = blockIdx.x * 256 + threadIdx.x;   // 65536
    int d = tid & 127;
    int c = (tid >> 7) & (NCH - 1);
    int b = tid >> 13;
    float u[16], r[16], we[16];
    #pragma unroll
    for (int h = 0; h < 16; ++h) {
        float a = sigmoidf_(alphas[h]);
        r[h] = (1.f - a) * sigmoidf_(damps[h]);
        we[h] = reduction[h * DD + d] * a * expansion[h * DD + d];
        u[h] = carry[((size_t)b * NCH + c) * 16 * DD + (size_t)h * DD + d];
    }
    const float* xp = x + ((size_t)b * LL + c * CHUNK) * DD + d;
    __hip_bfloat16* ep = emab + ((size_t)b * LL + c * CHUNK) * DD + d;
    __hip_bfloat16* xbp = xb + ((size_t)b * LL + c * CHUNK) * DD + d;
    #pragma unroll 4
    for (int i = 0; i < CHUNK; ++i) {
        float xv = xp[(size_t)i * DD];
        float acc = 0.f;
        #pragma unroll
        for (int h = 0; h < 16; ++h) {
            u[h] = fmaf(r[h], u[h], xv);
            acc = fmaf(we[h], u[h], acc);
        }
        ep[(size_t)i * DD] = f2bf(acc);
        xbp[(size_t)i * DD] = f2bf(xv);
    }
}

// ---------------- MFMA 64-row GEMM: C[64][N] = A[64][K] @ W[K][N] (+bias, act)
// MODE 0: QK (silu, gamma/beta -> q,k bf16)   MODE 1: V (silu -> vT bf16)
// MODE 2: RST (silu -> rst bf16 row-major)
template<int K, int N, int MODE>
__global__ __launch_bounds__(256) void gemm64(const __hip_bfloat16* __restrict__ A,
        const __hip_bfloat16* __restrict__ Wp, const float* __restrict__ bias,
        const float* __restrict__ gamma, const float* __restrict__ beta,
        __hip_bfloat16* __restrict__ out0, __hip_bfloat16* __restrict__ out1) {
    constexpr int K32 = K/32, N16 = N/16, KB = K*2;
    __shared__ char AsB[64*KB];
    const int row0 = blockIdx.x * 64;
    const int t = threadIdx.x, w = t>>6, lane = t&63, l16 = lane&15, l4 = lane>>4;
    constexpr int UPT = (64*KB/16)/256;
    #pragma unroll
    for (int p = 0; p < UPT; ++p) {
        int idx = p*256 + t;
        int row = idx / (KB/16), u = idx % (KB/16);
        uint4 d = *reinterpret_cast<const uint4*>(A + (size_t)(row0+row)*K + u*8);
        *reinterpret_cast<uint4*>(AsB + row*KB + ((u*16) ^ ((row&7)<<4))) = d;
    }
    __syncthreads();
    f32x4 acc[N16];
    #pragma unroll
    for (int n = 0; n < N16; ++n) acc[n] = (f32x4){0.f,0.f,0.f,0.f};
    const int arow = w*16 + l16;
    #pragma unroll
    for (int k32 = 0; k32 < K32; ++k32) {
        s16x8 af = *reinterpret_cast<const s16x8*>(AsB + arow*KB + ((k32*64 + l4*16) ^ ((arow&7)<<4)));
        #pragma unroll
        for (int n = 0; n < N16; ++n) {
            s16x8 bfr = *reinterpret_cast<const s16x8*>(Wp + ((size_t)(n*K32 + k32)*64 + lane)*8);
            acc[n] = __builtin_amdgcn_mfma_f32_16x16x32_bf16(af, bfr, acc[n], 0, 0, 0);
        }
    }
    #pragma unroll
    for (int n = 0; n < N16; ++n) {
        int col = n*16 + l16;
        float bb = bias[col];
        if (MODE == 0) {
            float g0 = gamma[col], g1 = gamma[N + col];
            float be0 = beta[col], be1 = beta[N + col];
            #pragma unroll
            for (int r = 0; r < 4; ++r) {
                int row = w*16 + l4*4 + r;
                float s = siluf_(acc[n][r] + bb);
                out0[(size_t)(row0+row)*N + col] = f2bf(s*g0 + be0);
                out1[(size_t)(row0+row)*N + col] = f2bf(s*g1 + be1);
            }
        } else if (MODE == 1) {
            int bb_i = row0 >> 11;
            int lpos0 = (row0 & 2047) + w*16 + l4*4;
            ushort pk[4];
            #pragma unroll
            for (int r = 0; r < 4; ++r) pk[r] = f2bfu(siluf_(acc[n][r] + bb));
            *reinterpret_cast<ushort4*>(out0 + ((size_t)bb_i*DVN + col)*LL + lpos0) = *reinterpret_cast<ushort4*>(pk);
        } else {
            #pragma unroll
            for (int r = 0; r < 4; ++r) {
                int row = w*16 + l4*4 + r;
                out0[(size_t)(row0+row)*N + col] = f2bf(siluf_(acc[n][r] + bb));
            }
        }
    }
}

// ---------------- MFMA flash attention, double-buffered KV, bf16 out
__global__ __launch_bounds__(256) void attn_kernel(
    const __hip_bfloat16* __restrict__ qg, const __hip_bfloat16* __restrict__ kg,
    const __hip_bfloat16* __restrict__ vTg, const float* __restrict__ btab,
    __hip_bfloat16* __restrict__ aob) {
    __shared__ __hip_bfloat16 Ks[2][64 * 64];
    __shared__ __hip_bfloat16 Vs[2][256 * 64];
    __shared__ __hip_bfloat16 Ps[4][16][72];
    __shared__ float btabs[2048];
    const int b = blockIdx.x;          // XCD-locality: batch per XCD
    const int ti = blockIdx.y;
    const int i0 = ti * 64;
    const int t = threadIdx.x;
    const int w = t >> 6, lane = t & 63;
    const int l16 = lane & 15, l4 = lane >> 4;
    char* KsB = (char*)Ks;
    char* VsB = (char*)Vs;

    for (int idx = t; idx < LL; idx += 256) btabs[idx] = btab[idx];

    const int irow = i0 + w * 16 + l16;
    s16x8 qf[2];
    qf[0] = *reinterpret_cast<const s16x8*>(qg + ((size_t)b * LL + irow) * DQKN + l4 * 8);
    qf[1] = *reinterpret_cast<const s16x8*>(qg + ((size_t)b * LL + irow) * DQKN + 32 + l4 * 8);

    f32x4 o[16];
    #pragma unroll
    for (int n16 = 0; n16 < 16; ++n16) o[n16] = (f32x4){0.f, 0.f, 0.f, 0.f};
    float m[4] = {-1e30f, -1e30f, -1e30f, -1e30f};
    float l[4] = {0.f, 0.f, 0.f, 0.f};

    uint4 kreg[2], vreg[8];
    const int krow_ = t >> 3, kc_ = (t & 7);           // for p-th chunk: row = p*32 + krow_? (see below)
    // K tile: idx = p*256+t -> row = idx>>3 (0..63), c16 = idx&7
    // V tile: idx = p*256+t -> n = idx>>3 (0..255), c16 = idx&7

    #define LOADK(J0) { _Pragma("unroll") for (int p = 0; p < 2; ++p) { \
        int idx = p*256 + t; int row = idx >> 3, c16 = idx & 7; \
        kreg[p] = *reinterpret_cast<const uint4*>(kg + ((size_t)b * LL + (J0) + row) * DQKN + c16 * 8); } }
    #define LOADV(J0) { _Pragma("unroll") for (int p = 0; p < 8; ++p) { \
        int idx = p*256 + t; int n = idx >> 3, c16 = idx & 7; \
        vreg[p] = *reinterpret_cast<const uint4*>(vTg + ((size_t)b * DVN + n) * LL + (J0) + c16 * 8); } }
    #define WRITEK(BUF) { _Pragma("unroll") for (int p = 0; p < 2; ++p) { \
        int idx = p*256 + t; int row = idx >> 3, c16 = idx & 7; \
        *reinterpret_cast<uint4*>(KsB + (BUF)*8192 + row * 128 + ((c16 * 16) ^ ((row & 7) << 4))) = kreg[p]; } }
    #define WRITEV(BUF) { _Pragma("unroll") for (int p = 0; p < 8; ++p) { \
        int idx = p*256 + t; int n = idx >> 3, c16 = idx & 7; \
        *reinterpret_cast<uint4*>(VsB + (BUF)*32768 + n * 128 + ((c16 * 16) ^ ((n & 7) << 4))) = vreg[p]; } }

    LOADK(0); LOADV(0);
    WRITEK(0); WRITEV(0);
    __syncthreads();

    for (int tj = 0; tj <= ti; ++tj) {
        const int j0 = tj * 64;
        const int cur = tj & 1, nxt = cur ^ 1;
        const bool pre = (tj < ti);
        if (pre) { LOADK(j0 + 64); LOADV(j0 + 64); }
        // QK^T
        f32x4 s[4];
        #pragma unroll
        for (int t16 = 0; t16 < 4; ++t16) s[t16] = (f32x4){0.f, 0.f, 0.f, 0.f};
        #pragma unroll
        for (int c = 0; c < 2; ++c) {
            #pragma unroll
            for (int t16 = 0; t16 < 4; ++t16) {
                int j = t16 * 16 + l16;
                s16x8 kf = *reinterpret_cast<const s16x8*>(KsB + cur*8192 + j * 128 + ((c * 64 + l4 * 16) ^ ((j & 7) << 4)));
                s[t16] = __builtin_amdgcn_mfma_f32_16x16x32_bf16(qf[c], kf, s[t16], 0, 0, 0);
            }
        }
        float sv[4][4];
        float rmax[4] = {-1e30f, -1e30f, -1e30f, -1e30f};
        #pragma unroll
        for (int t16 = 0; t16 < 4; ++t16) {
            #pragma unroll
            for (int r = 0; r < 4; ++r) {
                int row = l4 * 4 + r;
                int dlt = (i0 + w * 16 + row) - (j0 + t16 * 16 + l16);
                float bv = btabs[dlt & 2047];
                float val = (dlt >= 0) ? (s[t16][r] * SCALE + bv) : -1e30f;
                sv[t16][r] = val;
                rmax[r] = fmaxf(rmax[r], val);
            }
        }
        #pragma unroll
        for (int off = 1; off < 16; off <<= 1) {
            #pragma unroll
            for (int r = 0; r < 4; ++r) rmax[r] = fmaxf(rmax[r], __shfl_xor(rmax[r], off));
        }
        float alpha[4], psum[4];
        #pragma unroll
        for (int r = 0; r < 4; ++r) {
            float mn = fmaxf(m[r], rmax[r]);
            alpha[r] = __expf(m[r] - mn);
            m[r] = mn;
            psum[r] = 0.f;
        }
        #pragma unroll
        for (int t16 = 0; t16 < 4; ++t16) {
            #pragma unroll
            for (int r = 0; r < 4; ++r) {
                float p = __expf(sv[t16][r] - m[r]);
                psum[r] += p;
                Ps[w][l4 * 4 + r][t16 * 16 + l16] = f2bf(p);
            }
        }
        #pragma unroll
        for (int off = 1; off < 16; off <<= 1) {
            #pragma unroll
            for (int r = 0; r < 4; ++r) psum[r] += __shfl_xor(psum[r], off);
        }
        #pragma unroll
        for (int r = 0; r < 4; ++r) l[r] = l[r] * alpha[r] + psum[r];
        #pragma unroll
        for (int n16 = 0; n16 < 16; ++n16) {
            #pragma unroll
            for (int r = 0; r < 4; ++r) o[n16][r] *= alpha[r];
        }
        // PV (Ps is wave-private; lgkmcnt ordering handled by compiler)
        #pragma unroll
        for (int c = 0; c < 2; ++c) {
            s16x8 pf = *reinterpret_cast<const s16x8*>(&Ps[w][l16][c * 32 + l4 * 8]);
            #pragma unroll
            for (int n16 = 0; n16 < 16; ++n16) {
                int n = n16 * 16 + l16;
                s16x8 vf = *reinterpret_cast<const s16x8*>(VsB + cur*32768 + n * 128 + ((c * 64 + l4 * 16) ^ ((n & 7) << 4)));
                o[n16] = __builtin_amdgcn_mfma_f32_16x16x32_bf16(pf, vf, o[n16], 0, 0, 0);
            }
        }
        if (pre) { WRITEK(nxt); WRITEV(nxt); }
        __syncthreads();
    }
    float invl[4];
    #pragma unroll
    for (int r = 0; r < 4; ++r) invl[r] = 1.f / l[r];
    #pragma unroll
    for (int n16 = 0; n16 < 16; ++n16) {
        #pragma unroll
        for (int r = 0; r < 4; ++r) {
            aob[((size_t)b * LL + i0 + w * 16 + l4 * 4 + r) * DVN + n16 * 16 + l16] = f2bf(o[n16][r] * invl[r]);
        }
    }
    #undef LOADK
    #undef LOADV
    #undef WRITEK
    #undef WRITEV
}

// ---------------- fused final: D1 = ema@Wh + (ao*rst)@Uh + bh (silu);
//                  D2 = ema@W_update + b_update (sigmoid); out = u*Hh + (1-u)*x
__global__ __launch_bounds__(256) void final_mfma(
        const __hip_bfloat16* __restrict__ emab, const __hip_bfloat16* __restrict__ aob,
        const __hip_bfloat16* __restrict__ rstb, const float* __restrict__ x,
        const __hip_bfloat16* __restrict__ WhP, const __hip_bfloat16* __restrict__ UhP,
        const __hip_bfloat16* __restrict__ WuP, const float* __restrict__ bh,
        const float* __restrict__ bu, float* __restrict__ out) {
    __shared__ char As1[64*256];   // ema tile, K=128
    __shared__ char As2[64*512];   // gated tile, K=256
    const int row0 = blockIdx.x * 64;
    const int t = threadIdx.x, w = t>>6, lane = t&63, l16 = lane&15, l4 = lane>>4;
    #pragma unroll
    for (int p = 0; p < 4; ++p) {
        int idx = p*256 + t;
        int row = idx / 16, u = idx % 16;
        uint4 d = *reinterpret_cast<const uint4*>(emab + (size_t)(row0+row)*DD + u*8);
        *reinterpret_cast<uint4*>(As1 + row*256 + ((u*16) ^ ((row&7)<<4))) = d;
    }
    #pragma unroll
    for (int p = 0; p < 8; ++p) {
        int idx = p*256 + t;
        int row = idx / 32, u = idx % 32;
        uint4 da = *reinterpret_cast<const uint4*>(aob + (size_t)(row0+row)*DVN + u*8);
        uint4 dr = *reinterpret_cast<const uint4*>(rstb + (size_t)(row0+row)*DVN + u*8);
        const ushort* pa = (const ushort*)&da;
        const ushort* pr = (const ushort*)&dr;
        ushort g[8];
        #pragma unroll
        for (int j = 0; j < 8; ++j) g[j] = f2bfu(bf2f(pa[j]) * bf2f(pr[j]));
        *reinterpret_cast<uint4*>(As2 + row*512 + ((u*16) ^ ((row&7)<<4))) = *reinterpret_cast<uint4*>(g);
    }
    __syncthreads();
    f32x4 acc1[8], acc2[8];
    #pragma unroll
    for (int n = 0; n < 8; ++n) { acc1[n] = (f32x4){0.f,0.f,0.f,0.f}; acc2[n] = (f32x4){0.f,0.f,0.f,0.f}; }
    const int arow = w*16 + l16;
    #pragma unroll
    for (int k32 = 0; k32 < 4; ++k32) {
        s16x8 af = *reinterpret_cast<const s16x8*>(As1 + arow*256 + ((k32*64 + l4*16) ^ ((arow&7)<<4)));
        #pragma unroll
        for (int n = 0; n < 8; ++n) {
            s16x8 bw = *reinterpret_cast<const s16x8*>(WhP + ((size_t)(n*4 + k32)*64 + lane)*8);
            acc1[n] = __builtin_amdgcn_mfma_f32_16x16x32_bf16(af, bw, acc1[n], 0, 0, 0);
            s16x8 bu2 = *reinterpret_cast<const s16x8*>(WuP + ((size_t)(n*4 + k32)*64 + lane)*8);
            acc2[n] = __builtin_amdgcn_mfma_f32_16x16x32_bf16(af, bu2, acc2[n], 0, 0, 0);
        }
    }
    #pragma unroll
    for (int k32 = 0; k32 < 8; ++k32) {
        s16x8 gf = *reinterpret_cast<const s16x8*>(As2 + arow*512 + ((k32*64 + l4*16) ^ ((arow&7)<<4)));
        #pragma unroll
        for (int n = 0; n < 8; ++n) {
            s16x8 bw = *reinterpret_cast<const s16x8*>(UhP + ((size_t)(n*8 + k32)*64 + lane)*8);
            acc1[n] = __builtin_amdgcn_mfma_f32_16x16x32_bf16(gf, bw, acc1[n], 0, 0, 0);
        }
    }
    #pragma unroll
    for (int n = 0; n < 8; ++n) {
        int col = n*16 + l16;
        float bbh = bh[col], bbu = bu[col];
        #pragma unroll
        for (int r = 0; r < 4; ++r) {
            int row = w*16 + l4*4 + r;
            size_t gidx = (size_t)(row0+row)*DD + col;
            float hh = siluf_(acc1[n][r] + bbh);
            float u = sigmoidf_(acc2[n][r] + bbu);
            float xv = x[gidx];
            out[gidx] = u*hh + (1.f-u)*xv;
        }
    }
}

extern "C" void kernel_launch(void* const* d_in, const int* in_sizes, int n_in,
                              void* d_out, int out_size, void* d_ws, size_t ws_size,
                              hipStream_t stream) {
    const float* x        = (const float*)d_in[0];
    const float* expansion= (const float*)d_in[1];
    const float* reduction= (const float*)d_in[2];
    const float* alphas   = (const float*)d_in[3];
    const float* damps    = (const float*)d_in[4];
    const float* rel_bias = (const float*)d_in[5];
    const float* W_qk     = (const float*)d_in[6];
    const float* b_qk     = (const float*)d_in[7];
    const float* gamma    = (const float*)d_in[8];
    const float* beta     = (const float*)d_in[9];
    const float* W_v      = (const float*)d_in[10];
    const float* b_v      = (const float*)d_in[11];
    const float* W_reset  = (const float*)d_in[12];
    const float* b_reset  = (const float*)d_in[13];
    const float* W_update = (const float*)d_in[14];
    const float* b_update = (const float*)d_in[15];
    const float* Wh       = (const float*)d_in[16];
    const float* Uh       = (const float*)d_in[17];
    const float* bh       = (const float*)d_in[18];
    float* out = (float*)d_out;

    char* base = (char*)d_ws;
    __hip_bfloat16* emab = (__hip_bfloat16*)base;  base += (size_t)MTOT * DD * 2;
    __hip_bfloat16* xb   = (__hip_bfloat16*)base;  base += (size_t)MTOT * DD * 2;
    __hip_bfloat16* qb   = (__hip_bfloat16*)base;  base += (size_t)MTOT * DQKN * 2;
    __hip_bfloat16* kb   = (__hip_bfloat16*)base;  base += (size_t)MTOT * DQKN * 2;
    __hip_bfloat16* vT   = (__hip_bfloat16*)base;  base += (size_t)MTOT * DVN * 2;
    __hip_bfloat16* rstb = (__hip_bfloat16*)base;  base += (size_t)MTOT * DVN * 2;
    __hip_bfloat16* aob  = (__hip_bfloat16*)base;  base += (size_t)MTOT * DVN * 2;
    float* btab  = (float*)base;                   base += (size_t)LL * 4;
    float* sl    = (float*)base;                   base += (size_t)BB * NCH * 16 * DD * 4;
    float* carry = (float*)base;                   base += (size_t)BB * NCH * 16 * DD * 4;
    __hip_bfloat16* WqkP = (__hip_bfloat16*)base;  base += (size_t)DD * DQKN * 2;
    __hip_bfloat16* WvP  = (__hip_bfloat16*)base;  base += (size_t)DD * DVN * 2;
    __hip_bfloat16* WrstP= (__hip_bfloat16*)base;  base += (size_t)DD * DVN * 2;
    __hip_bfloat16* WuP  = (__hip_bfloat16*)base;  base += (size_t)DD * DD * 2;
    __hip_bfloat16* WhP  = (__hip_bfloat16*)base;  base += (size_t)DD * DD * 2;
    __hip_bfloat16* UhP  = (__hip_bfloat16*)base;  base += (size_t)DVN * DD * 2;

    bias_kernel<<<8, 256, 0, stream>>>(rel_bias, btab);
    pack_w<128,64> <<<(64/16)*(128/32), 64, 0, stream>>>(W_qk,     WqkP);
    pack_w<128,256><<<(256/16)*(128/32), 64, 0, stream>>>(W_v,     WvP);
    pack_w<128,256><<<(256/16)*(128/32), 64, 0, stream>>>(W_reset, WrstP);
    pack_w<128,128><<<(128/16)*(128/32), 64, 0, stream>>>(W_update,WuP);
    pack_w<128,128><<<(128/16)*(128/32), 64, 0, stream>>>(Wh,      WhP);
    pack_w<256,128><<<(128/16)*(256/32), 64, 0, stream>>>(Uh,      UhP);

    ema_scanA<<<BB * NCH * DD / 256, 256, 0, stream>>>(x, alphas, damps, sl);
    ema_scanB<<<BB * 16 * DD / 256, 256, 0, stream>>>(alphas, damps, sl, carry);
    ema_scanC<<<BB * NCH * DD / 256, 256, 0, stream>>>(x, expansion, reduction, alphas, damps, carry, emab, xb);

    gemm64<128,64,0> <<<MTOT/64, 256, 0, stream>>>(emab, WqkP, b_qk,   gamma, beta, qb, kb);
    gemm64<128,256,1><<<MTOT/64, 256, 0, stream>>>(xb,   WvP,  b_v,    nullptr, nullptr, vT, nullptr);
    gemm64<128,256,2><<<MTOT/64, 256, 0, stream>>>(emab, WrstP,b_reset,nullptr, nullptr, rstb, nullptr);

    attn_kernel<<<dim3(BB, LL/64), 256, 0, stream>>>(qb, kb, vT, btab, aob);

    final_mfma<<<MTOT/64, 256, 0, stream>>>(emab, aob, rstb, x, WhP, UhP, WuP, bh, b_update, out);
}

// Round 5
// 213.345 us; speedup vs baseline: 22.9680x; 1.3507x over previous
//
#include <hip/hip_runtime.h>
#include <hip/hip_bf16.h>
#include <math.h>

#define BB 8
#define LL 2048
#define DD 128
#define DQKN 64
#define DVN 256
#define MTOT (BB*LL)
#define SCALE 0.08838834764831845f  // 128^-0.5

#define CHUNK 32
#define NCH (LL/CHUNK)   // 64
#define CT 8             // KV tiles (of 64) per attn chunk-block

typedef __attribute__((ext_vector_type(4))) float f32x4;
typedef __attribute__((ext_vector_type(8))) short s16x8;

__device__ __forceinline__ float sigmoidf_(float x){ return 1.f/(1.f+__expf(-x)); }
__device__ __forceinline__ float siluf_(float x){ return x/(1.f+__expf(-x)); }
__device__ __forceinline__ __hip_bfloat16 f2bf(float f){ return __float2bfloat16(f); }
__device__ __forceinline__ ushort f2bfu(float f){ __hip_bfloat16 h = __float2bfloat16(f); return *(const ushort*)&h; }
__device__ __forceinline__ float bf2f(ushort u){ union{unsigned i; float f;} v; v.i = ((unsigned)u)<<16; return v.f; }

// ---------------- bias table: btab[n] = rel_bias[bucket(n)] * sqrt(DQK)
__global__ void bias_kernel(const float* __restrict__ rel_bias, float* __restrict__ btab) {
    int n = blockIdx.x * blockDim.x + threadIdx.x;
    if (n >= LL) return;
    int bucket;
    if (n < 16) bucket = n;
    else {
        float v = logf((float)n * (1.0f/16.0f)) * (1.0f/logf(8.0f)) * 16.0f;
        bucket = 16 + (int)v;
        if (bucket > 31) bucket = 31;
    }
    btab[n] = rel_bias[bucket] * 8.0f;
}

// ---------------- pack W[K][N] fp32 -> bf16 MFMA B-fragments
template<int K, int N>
__global__ void pack_w(const float* __restrict__ W, __hip_bfloat16* __restrict__ Wp) {
    int blk = blockIdx.x;            // n16*(K/32) + k32
    int l = threadIdx.x;             // 64
    int k32 = blk % (K/32), n16 = blk / (K/32);
    int col = n16*16 + (l & 15);
    int krow = k32*32 + (l >> 4)*8;
    ushort tmp[8];
    #pragma unroll
    for (int j = 0; j < 8; ++j) tmp[j] = f2bfu(W[(size_t)(krow + j)*N + col]);
    *reinterpret_cast<uint4*>(Wp + ((size_t)blk*64 + l)*8) = *reinterpret_cast<uint4*>(tmp);
}

// ---------------- EMA chunked scan
__global__ __launch_bounds__(256) void ema_scanA(const float* __restrict__ x,
                                                 const float* __restrict__ alphas,
                                                 const float* __restrict__ damps,
                                                 float* __restrict__ sl) {
    int tid = blockIdx.x * 256 + threadIdx.x;   // 65536
    int d = tid & 127;
    int c = (tid >> 7) & (NCH - 1);
    int b = tid >> 13;
    float u[16], r[16];
    #pragma unroll
    for (int h = 0; h < 16; ++h) {
        float a = sigmoidf_(alphas[h]);
        r[h] = (1.f - a) * sigmoidf_(damps[h]);
        u[h] = 0.f;
    }
    const float* xp = x + ((size_t)b * LL + c * CHUNK) * DD + d;
    #pragma unroll 4
    for (int i = 0; i < CHUNK; ++i) {
        float xv = xp[(size_t)i * DD];
        #pragma unroll
        for (int h = 0; h < 16; ++h) u[h] = fmaf(r[h], u[h], xv);
    }
    float* slp = sl + ((size_t)b * NCH + c) * 16 * DD + d;
    #pragma unroll
    for (int h = 0; h < 16; ++h) slp[(size_t)h * DD] = u[h];
}

__global__ __launch_bounds__(256) void ema_scanB(const float* __restrict__ alphas,
                                                 const float* __restrict__ damps,
                                                 const float* __restrict__ sl,
                                                 float* __restrict__ carry) {
    int tid = blockIdx.x * 256 + threadIdx.x;   // 16384
    int d = tid & 127;
    int h = (tid >> 7) & 15;
    int b = tid >> 11;
    float a = sigmoidf_(alphas[h]);
    float r = (1.f - a) * sigmoidf_(damps[h]);
    float rC = r;
    #pragma unroll
    for (int q = 0; q < 5; ++q) rC *= rC;       // r^32
    const float* slp = sl + ((size_t)b * NCH * 16 + h) * DD + d;
    float* cp = carry + ((size_t)b * NCH * 16 + h) * DD + d;
    float u = 0.f;
    for (int c = 0; c < NCH; ++c) {
        cp[(size_t)c * 16 * DD] = u;
        u = slp[(size_t)c * 16 * DD] + rC * u;
    }
}

__global__ __launch_bounds__(256) void ema_scanC(const float* __restrict__ x,
                                                 const float* __restrict__ expansion,
                                                 const float* __restrict__ reduction,
                                                 const float* __restrict__ alphas,
                                                 const float* __restrict__ damps,
                                                 const float* __restrict__ carry,
                                                 __hip_bfloat16* __restrict__ emab,
                                                 __hip_bfloat16* __restrict__ xb) {
    int tid = blockIdx.x * 256 + threadIdx.x;   // 65536
    int d = tid & 127;
    int c = (tid >> 7) & (NCH - 1);
    int b = tid >> 13;
    float u[16], r[16], we[16];
    #pragma unroll
    for (int h = 0; h < 16; ++h) {
        float a = sigmoidf_(alphas[h]);
        r[h] = (1.f - a) * sigmoidf_(damps[h]);
        we[h] = reduction[h * DD + d] * a * expansion[h * DD + d];
        u[h] = carry[((size_t)b * NCH + c) * 16 * DD + (size_t)h * DD + d];
    }
    const float* xp = x + ((size_t)b * LL + c * CHUNK) * DD + d;
    __hip_bfloat16* ep = emab + ((size_t)b * LL + c * CHUNK) * DD + d;
    __hip_bfloat16* xbp = xb + ((size_t)b * LL + c * CHUNK) * DD + d;
    #pragma unroll 4
    for (int i = 0; i < CHUNK; ++i) {
        float xv = xp[(size_t)i * DD];
        float acc = 0.f;
        #pragma unroll
        for (int h = 0; h < 16; ++h) {
            u[h] = fmaf(r[h], u[h], xv);
            acc = fmaf(we[h], u[h], acc);
        }
        ep[(size_t)i * DD] = f2bf(acc);
        xbp[(size_t)i * DD] = f2bf(xv);
    }
}

// ---------------- MFMA 64-row GEMM
// MODE 0: QK (silu, gamma/beta -> q,k)  MODE 1: V (silu -> vT)  MODE 2: RST (silu)
template<int K, int N, int MODE>
__global__ __launch_bounds__(256) void gemm64(const __hip_bfloat16* __restrict__ A,
        const __hip_bfloat16* __restrict__ Wp, const float* __restrict__ bias,
        const float* __restrict__ gamma, const float* __restrict__ beta,
        __hip_bfloat16* __restrict__ out0, __hip_bfloat16* __restrict__ out1) {
    constexpr int K32 = K/32, N16 = N/16, KB = K*2;
    __shared__ char AsB[64*KB];
    const int row0 = blockIdx.x * 64;
    const int t = threadIdx.x, w = t>>6, lane = t&63, l16 = lane&15, l4 = lane>>4;
    constexpr int UPT = (64*KB/16)/256;
    #pragma unroll
    for (int p = 0; p < UPT; ++p) {
        int idx = p*256 + t;
        int row = idx / (KB/16), u = idx % (KB/16);
        uint4 d = *reinterpret_cast<const uint4*>(A + (size_t)(row0+row)*K + u*8);
        *reinterpret_cast<uint4*>(AsB + row*KB + ((u*16) ^ ((row&7)<<4))) = d;
    }
    __syncthreads();
    f32x4 acc[N16];
    #pragma unroll
    for (int n = 0; n < N16; ++n) acc[n] = (f32x4){0.f,0.f,0.f,0.f};
    const int arow = w*16 + l16;
    #pragma unroll
    for (int k32 = 0; k32 < K32; ++k32) {
        s16x8 af = *reinterpret_cast<const s16x8*>(AsB + arow*KB + ((k32*64 + l4*16) ^ ((arow&7)<<4)));
        #pragma unroll
        for (int n = 0; n < N16; ++n) {
            s16x8 bfr = *reinterpret_cast<const s16x8*>(Wp + ((size_t)(n*K32 + k32)*64 + lane)*8);
            acc[n] = __builtin_amdgcn_mfma_f32_16x16x32_bf16(af, bfr, acc[n], 0, 0, 0);
        }
    }
    #pragma unroll
    for (int n = 0; n < N16; ++n) {
        int col = n*16 + l16;
        float bb = bias[col];
        if (MODE == 0) {
            float g0 = gamma[col], g1 = gamma[N + col];
            float be0 = beta[col], be1 = beta[N + col];
            #pragma unroll
            for (int r = 0; r < 4; ++r) {
                int row = w*16 + l4*4 + r;
                float s = siluf_(acc[n][r] + bb);
                out0[(size_t)(row0+row)*N + col] = f2bf(s*g0 + be0);
                out1[(size_t)(row0+row)*N + col] = f2bf(s*g1 + be1);
            }
        } else if (MODE == 1) {
            int bb_i = row0 >> 11;
            int lpos0 = (row0 & 2047) + w*16 + l4*4;
            ushort pk[4];
            #pragma unroll
            for (int r = 0; r < 4; ++r) pk[r] = f2bfu(siluf_(acc[n][r] + bb));
            *reinterpret_cast<ushort4*>(out0 + ((size_t)bb_i*DVN + col)*LL + lpos0) = *reinterpret_cast<ushort4*>(pk);
        } else {
            #pragma unroll
            for (int r = 0; r < 4; ++r) {
                int row = w*16 + l4*4 + r;
                out0[(size_t)(row0+row)*N + col] = f2bf(siluf_(acc[n][r] + bb));
            }
        }
    }
}

// ---------------- MFMA flash attention, split-KV (chunks of CT tiles), partials + combine
__global__ __launch_bounds__(256) void attn_kernel(
    const __hip_bfloat16* __restrict__ qg, const __hip_bfloat16* __restrict__ kg,
    const __hip_bfloat16* __restrict__ vTg, const float* __restrict__ btab,
    __hip_bfloat16* __restrict__ aob, float* __restrict__ part_o,
    float* __restrict__ part_ml) {
    __shared__ __hip_bfloat16 Ks[64 * 64];      // swizzled
    __shared__ __hip_bfloat16 Vs[256 * 64];     // vT tile, swizzled
    __shared__ __hip_bfloat16 Ps[4][16][72];
    __shared__ float btl[576];
    const int cid = blockIdx.x;                 // 0..79
    const int b = blockIdx.y;
    int ti, cch;
    if (cid < 8)       { ti = cid;                 cch = 0; }
    else if (cid < 24) { ti = 8  + ((cid-8)>>1);   cch = (cid-8)&1; }
    else if (cid < 48) { ti = 16 + (cid-24)/3;     cch = (cid-24)%3; }
    else               { ti = 24 + ((cid-48)>>2);  cch = (cid-48)&3; }
    const int i0 = ti * 64;
    const int jlo = cch * (CT*64);
    int jhi = jlo + CT*64; { int je = (ti+1)*64; if (jhi > je) jhi = je; }
    const int nt = (jhi - jlo) >> 6;
    const int t = threadIdx.x;
    const int w = t >> 6, lane = t & 63;
    const int l16 = lane & 15, l4 = lane >> 4;
    char* KsB = (char*)Ks;
    char* VsB = (char*)Vs;

    int dmin = i0 - jhi + 1; if (dmin < 0) dmin = 0;
    const int cnt = (i0 + 63 - jlo) - dmin + 1;
    for (int idx = t; idx < cnt; idx += 256) btl[idx] = btab[dmin + idx];

    const int irow = i0 + w * 16 + l16;
    s16x8 qf[2];
    qf[0] = *reinterpret_cast<const s16x8*>(qg + ((size_t)b * LL + irow) * DQKN + l4 * 8);
    qf[1] = *reinterpret_cast<const s16x8*>(qg + ((size_t)b * LL + irow) * DQKN + 32 + l4 * 8);

    f32x4 o[16];
    #pragma unroll
    for (int n16 = 0; n16 < 16; ++n16) o[n16] = (f32x4){0.f, 0.f, 0.f, 0.f};
    float m[4] = {-1e30f, -1e30f, -1e30f, -1e30f};
    float l[4] = {0.f, 0.f, 0.f, 0.f};

    for (int tt = 0; tt < nt; ++tt) {
        const int j0 = jlo + tt * 64;
        __syncthreads();
        // stage K tile 64x64 (8KB)
        #pragma unroll
        for (int p = 0; p < 2; ++p) {
            int idx = p * 256 + t;
            int row = idx >> 3, c16 = idx & 7;
            uint4 d = *reinterpret_cast<const uint4*>(kg + ((size_t)b * LL + j0 + row) * DQKN + c16 * 8);
            *reinterpret_cast<uint4*>(KsB + row * 128 + ((c16 * 16) ^ ((row & 7) << 4))) = d;
        }
        // stage V^T tile 256x64 (32KB)
        #pragma unroll
        for (int p = 0; p < 8; ++p) {
            int idx = p * 256 + t;
            int n = idx >> 3, c16 = idx & 7;
            uint4 d = *reinterpret_cast<const uint4*>(vTg + ((size_t)b * DVN + n) * LL + j0 + c16 * 8);
            *reinterpret_cast<uint4*>(VsB + n * 128 + ((c16 * 16) ^ ((n & 7) << 4))) = d;
        }
        __syncthreads();
        // QK^T
        f32x4 s[4];
        #pragma unroll
        for (int t16 = 0; t16 < 4; ++t16) s[t16] = (f32x4){0.f, 0.f, 0.f, 0.f};
        #pragma unroll
        for (int c = 0; c < 2; ++c) {
            #pragma unroll
            for (int t16 = 0; t16 < 4; ++t16) {
                int j = t16 * 16 + l16;
                s16x8 kf = *reinterpret_cast<const s16x8*>(KsB + j * 128 + ((c * 64 + l4 * 16) ^ ((j & 7) << 4)));
                s[t16] = __builtin_amdgcn_mfma_f32_16x16x32_bf16(qf[c], kf, s[t16], 0, 0, 0);
            }
        }
        // scale + bias + mask, row stats
        float sv[4][4];
        float rmax[4] = {-1e30f, -1e30f, -1e30f, -1e30f};
        #pragma unroll
        for (int t16 = 0; t16 < 4; ++t16) {
            #pragma unroll
            for (int r = 0; r < 4; ++r) {
                int row = l4 * 4 + r;
                int dlt = (i0 + w * 16 + row) - (j0 + t16 * 16 + l16);
                int bi = dlt - dmin; if (bi < 0) bi = 0;
                float bv = btl[bi];
                float val = (dlt >= 0) ? (s[t16][r] * SCALE + bv) : -1e30f;
                sv[t16][r] = val;
                rmax[r] = fmaxf(rmax[r], val);
            }
        }
        #pragma unroll
        for (int off = 1; off < 16; off <<= 1) {
            #pragma unroll
            for (int r = 0; r < 4; ++r) rmax[r] = fmaxf(rmax[r], __shfl_xor(rmax[r], off));
        }
        float alpha[4], psum[4];
        #pragma unroll
        for (int r = 0; r < 4; ++r) {
            float mn = fmaxf(m[r], rmax[r]);
            alpha[r] = __expf(m[r] - mn);
            m[r] = mn;
            psum[r] = 0.f;
        }
        #pragma unroll
        for (int t16 = 0; t16 < 4; ++t16) {
            #pragma unroll
            for (int r = 0; r < 4; ++r) {
                float p = __expf(sv[t16][r] - m[r]);
                psum[r] += p;
                Ps[w][l4 * 4 + r][t16 * 16 + l16] = f2bf(p);
            }
        }
        #pragma unroll
        for (int off = 1; off < 16; off <<= 1) {
            #pragma unroll
            for (int r = 0; r < 4; ++r) psum[r] += __shfl_xor(psum[r], off);
        }
        #pragma unroll
        for (int r = 0; r < 4; ++r) l[r] = l[r] * alpha[r] + psum[r];
        #pragma unroll
        for (int n16 = 0; n16 < 16; ++n16) {
            #pragma unroll
            for (int r = 0; r < 4; ++r) o[n16][r] *= alpha[r];
        }
        __syncthreads();
        // PV
        #pragma unroll
        for (int c = 0; c < 2; ++c) {
            s16x8 pf = *reinterpret_cast<const s16x8*>(&Ps[w][l16][c * 32 + l4 * 8]);
            #pragma unroll
            for (int n16 = 0; n16 < 16; ++n16) {
                int n = n16 * 16 + l16;
                s16x8 vf = *reinterpret_cast<const s16x8*>(VsB + n * 128 + ((c * 64 + l4 * 16) ^ ((n & 7) << 4)));
                o[n16] = __builtin_amdgcn_mfma_f32_16x16x32_bf16(pf, vf, o[n16], 0, 0, 0);
            }
        }
    }
    if (ti < 8) {
        // single chunk: finalize directly
        float invl[4];
        #pragma unroll
        for (int r = 0; r < 4; ++r) invl[r] = 1.f / l[r];
        #pragma unroll
        for (int n16 = 0; n16 < 16; ++n16) {
            #pragma unroll
            for (int r = 0; r < 4; ++r) {
                aob[((size_t)b * LL + i0 + w * 16 + l4 * 4 + r) * DVN + n16 * 16 + l16] = f2bf(o[n16][r] * invl[r]);
            }
        }
    } else {
        const size_t slot = (size_t)b * 80 + cid;
        float* po = part_o + slot * (64 * 256);
        #pragma unroll
        for (int n16 = 0; n16 < 16; ++n16) {
            #pragma unroll
            for (int r = 0; r < 4; ++r)
                po[(size_t)(w * 16 + l4 * 4 + r) * 256 + n16 * 16 + l16] = o[n16][r];
        }
        if (l16 == 0) {
            #pragma unroll
            for (int r = 0; r < 4; ++r) {
                int row = w * 16 + l4 * 4 + r;
                part_ml[slot * 128 + row * 2]     = m[r];
                part_ml[slot * 128 + row * 2 + 1] = l[r];
            }
        }
    }
}

// ---------------- combine partials (ti >= 8): out = sum_c w_c O_c / sum_c w_c l_c
__global__ __launch_bounds__(256) void attn_combine(const float* __restrict__ part_o,
                                                    const float* __restrict__ part_ml,
                                                    __hip_bfloat16* __restrict__ aob) {
    const int tix = blockIdx.x;       // 0..23 -> ti = 8+tix
    const int b = blockIdx.y;
    const int ti = 8 + tix;
    int nc, cid0;
    if (ti < 16)      { nc = 2; cid0 = 8  + (ti-8)*2; }
    else if (ti < 24) { nc = 3; cid0 = 24 + (ti-16)*3; }
    else              { nc = 4; cid0 = 48 + (ti-24)*4; }
    const size_t slot0 = (size_t)b * 80 + cid0;
    __shared__ float sW[4][64];
    __shared__ float sinvL[64];
    const int t = threadIdx.x;
    if (t < 64) {
        float mm[4], ll[4], M = -1e30f;
        for (int c = 0; c < nc; ++c) {
            mm[c] = part_ml[(slot0 + c) * 128 + t * 2];
            ll[c] = part_ml[(slot0 + c) * 128 + t * 2 + 1];
            M = fmaxf(M, mm[c]);
        }
        float L = 0.f;
        for (int c = 0; c < nc; ++c) {
            float wv = __expf(mm[c] - M);
            sW[c][t] = wv;
            L += wv * ll[c];
        }
        sinvL[t] = 1.f / L;
    }
    __syncthreads();
    const int i0 = ti * 64;
    #pragma unroll
    for (int it = 0; it < 16; ++it) {
        int idx = it * 256 + t;         // float4 units over 64x256
        int row = idx >> 6, c4 = idx & 63;
        f32x4 acc = (f32x4){0.f, 0.f, 0.f, 0.f};
        for (int c = 0; c < nc; ++c) {
            float wv = sW[c][row];
            f32x4 v = *reinterpret_cast<const f32x4*>(part_o + ((slot0 + c) * 64 + row) * 256 + c4 * 4);
            acc[0] = fmaf(wv, v[0], acc[0]);
            acc[1] = fmaf(wv, v[1], acc[1]);
            acc[2] = fmaf(wv, v[2], acc[2]);
            acc[3] = fmaf(wv, v[3], acc[3]);
        }
        float il = sinvL[row];
        ushort pk[4];
        #pragma unroll
        for (int j = 0; j < 4; ++j) pk[j] = f2bfu(acc[j] * il);
        *reinterpret_cast<ushort4*>(aob + ((size_t)b * LL + i0 + row) * DVN + c4 * 4) = *reinterpret_cast<ushort4*>(pk);
    }
}

// ---------------- fused final
__global__ __launch_bounds__(256) void final_mfma(
        const __hip_bfloat16* __restrict__ emab, const __hip_bfloat16* __restrict__ aob,
        const __hip_bfloat16* __restrict__ rstb, const float* __restrict__ x,
        const __hip_bfloat16* __restrict__ WhP, const __hip_bfloat16* __restrict__ UhP,
        const __hip_bfloat16* __restrict__ WuP, const float* __restrict__ bh,
        const float* __restrict__ bu, float* __restrict__ out) {
    __shared__ char As1[64*256];   // ema tile, K=128
    __shared__ char As2[64*512];   // gated tile, K=256
    const int row0 = blockIdx.x * 64;
    const int t = threadIdx.x, w = t>>6, lane = t&63, l16 = lane&15, l4 = lane>>4;
    #pragma unroll
    for (int p = 0; p < 4; ++p) {
        int idx = p*256 + t;
        int row = idx / 16, u = idx % 16;
        uint4 d = *reinterpret_cast<const uint4*>(emab + (size_t)(row0+row)*DD + u*8);
        *reinterpret_cast<uint4*>(As1 + row*256 + ((u*16) ^ ((row&7)<<4))) = d;
    }
    #pragma unroll
    for (int p = 0; p < 8; ++p) {
        int idx = p*256 + t;
        int row = idx / 32, u = idx % 32;
        uint4 da = *reinterpret_cast<const uint4*>(aob + (size_t)(row0+row)*DVN + u*8);
        uint4 dr = *reinterpret_cast<const uint4*>(rstb + (size_t)(row0+row)*DVN + u*8);
        const ushort* pa = (const ushort*)&da;
        const ushort* pr = (const ushort*)&dr;
        ushort g[8];
        #pragma unroll
        for (int j = 0; j < 8; ++j) g[j] = f2bfu(bf2f(pa[j]) * bf2f(pr[j]));
        *reinterpret_cast<uint4*>(As2 + row*512 + ((u*16) ^ ((row&7)<<4))) = *reinterpret_cast<uint4*>(g);
    }
    __syncthreads();
    f32x4 acc1[8], acc2[8];
    #pragma unroll
    for (int n = 0; n < 8; ++n) { acc1[n] = (f32x4){0.f,0.f,0.f,0.f}; acc2[n] = (f32x4){0.f,0.f,0.f,0.f}; }
    const int arow = w*16 + l16;
    #pragma unroll
    for (int k32 = 0; k32 < 4; ++k32) {
        s16x8 af = *reinterpret_cast<const s16x8*>(As1 + arow*256 + ((k32*64 + l4*16) ^ ((arow&7)<<4)));
        #pragma unroll
        for (int n = 0; n < 8; ++n) {
            s16x8 bw = *reinterpret_cast<const s16x8*>(WhP + ((size_t)(n*4 + k32)*64 + lane)*8);
            acc1[n] = __builtin_amdgcn_mfma_f32_16x16x32_bf16(af, bw, acc1[n], 0, 0, 0);
            s16x8 bu2 = *reinterpret_cast<const s16x8*>(WuP + ((size_t)(n*4 + k32)*64 + lane)*8);
            acc2[n] = __builtin_amdgcn_mfma_f32_16x16x32_bf16(af, bu2, acc2[n], 0, 0, 0);
        }
    }
    #pragma unroll
    for (int k32 = 0; k32 < 8; ++k32) {
        s16x8 gf = *reinterpret_cast<const s16x8*>(As2 + arow*512 + ((k32*64 + l4*16) ^ ((arow&7)<<4)));
        #pragma unroll
        for (int n = 0; n < 8; ++n) {
            s16x8 bw = *reinterpret_cast<const s16x8*>(UhP + ((size_t)(n*8 + k32)*64 + lane)*8);
            acc1[n] = __builtin_amdgcn_mfma_f32_16x16x32_bf16(gf, bw, acc1[n], 0, 0, 0);
        }
    }
    #pragma unroll
    for (int n = 0; n < 8; ++n) {
        int col = n*16 + l16;
        float bbh = bh[col], bbu = bu[col];
        #pragma unroll
        for (int r = 0; r < 4; ++r) {
            int row = w*16 + l4*4 + r;
            size_t gidx = (size_t)(row0+row)*DD + col;
            float hh = siluf_(acc1[n][r] + bbh);
            float u = sigmoidf_(acc2[n][r] + bbu);
            float xv = x[gidx];
            out[gidx] = u*hh + (1.f-u)*xv;
        }
    }
}

extern "C" void kernel_launch(void* const* d_in, const int* in_sizes, int n_in,
                              void* d_out, int out_size, void* d_ws, size_t ws_size,
                              hipStream_t stream) {
    const float* x        = (const float*)d_in[0];
    const float* expansion= (const float*)d_in[1];
    const float* reduction= (const float*)d_in[2];
    const float* alphas   = (const float*)d_in[3];
    const float* damps    = (const float*)d_in[4];
    const float* rel_bias = (const float*)d_in[5];
    const float* W_qk     = (const float*)d_in[6];
    const float* b_qk     = (const float*)d_in[7];
    const float* gamma    = (const float*)d_in[8];
    const float* beta     = (const float*)d_in[9];
    const float* W_v      = (const float*)d_in[10];
    const float* b_v      = (const float*)d_in[11];
    const float* W_reset  = (const float*)d_in[12];
    const float* b_reset  = (const float*)d_in[13];
    const float* W_update = (const float*)d_in[14];
    const float* b_update = (const float*)d_in[15];
    const float* Wh       = (const float*)d_in[16];
    const float* Uh       = (const float*)d_in[17];
    const float* bh       = (const float*)d_in[18];
    float* out = (float*)d_out;

    char* base = (char*)d_ws;
    __hip_bfloat16* emab = (__hip_bfloat16*)base;  base += (size_t)MTOT * DD * 2;
    __hip_bfloat16* xb   = (__hip_bfloat16*)base;  base += (size_t)MTOT * DD * 2;
    __hip_bfloat16* qb   = (__hip_bfloat16*)base;  base += (size_t)MTOT * DQKN * 2;
    __hip_bfloat16* kb   = (__hip_bfloat16*)base;  base += (size_t)MTOT * DQKN * 2;
    __hip_bfloat16* vT   = (__hip_bfloat16*)base;  base += (size_t)MTOT * DVN * 2;
    __hip_bfloat16* rstb = (__hip_bfloat16*)base;  base += (size_t)MTOT * DVN * 2;
    __hip_bfloat16* aob  = (__hip_bfloat16*)base;  base += (size_t)MTOT * DVN * 2;
    float* btab  = (float*)base;                   base += (size_t)LL * 4;
    float* sl    = (float*)base;                   base += (size_t)BB * NCH * 16 * DD * 4;
    float* carry = (float*)base;                   base += (size_t)BB * NCH * 16 * DD * 4;
    __hip_bfloat16* WqkP = (__hip_bfloat16*)base;  base += (size_t)DD * DQKN * 2;
    __hip_bfloat16* WvP  = (__hip_bfloat16*)base;  base += (size_t)DD * DVN * 2;
    __hip_bfloat16* WrstP= (__hip_bfloat16*)base;  base += (size_t)DD * DVN * 2;
    __hip_bfloat16* WuP  = (__hip_bfloat16*)base;  base += (size_t)DD * DD * 2;
    __hip_bfloat16* WhP  = (__hip_bfloat16*)base;  base += (size_t)DD * DD * 2;
    __hip_bfloat16* UhP  = (__hip_bfloat16*)base;  base += (size_t)DVN * DD * 2;
    float* part_o  = (float*)base;                 base += (size_t)BB * 80 * 64 * 256 * 4;
    float* part_ml = (float*)base;                 base += (size_t)BB * 80 * 128 * 4;

    bias_kernel<<<8, 256, 0, stream>>>(rel_bias, btab);
    pack_w<128,64> <<<(64/16)*(128/32), 64, 0, stream>>>(W_qk,     WqkP);
    pack_w<128,256><<<(256/16)*(128/32), 64, 0, stream>>>(W_v,     WvP);
    pack_w<128,256><<<(256/16)*(128/32), 64, 0, stream>>>(W_reset, WrstP);
    pack_w<128,128><<<(128/16)*(128/32), 64, 0, stream>>>(W_update,WuP);
    pack_w<128,128><<<(128/16)*(128/32), 64, 0, stream>>>(Wh,      WhP);
    pack_w<256,128><<<(128/16)*(256/32), 64, 0, stream>>>(Uh,      UhP);

    ema_scanA<<<BB * NCH * DD / 256, 256, 0, stream>>>(x, alphas, damps, sl);
    ema_scanB<<<BB * 16 * DD / 256, 256, 0, stream>>>(alphas, damps, sl, carry);
    ema_scanC<<<BB * NCH * DD / 256, 256, 0, stream>>>(x, expansion, reduction, alphas, damps, carry, emab, xb);

    gemm64<128,64,0> <<<MTOT/64, 256, 0, stream>>>(emab, WqkP, b_qk,   gamma, beta, qb, kb);
    gemm64<128,256,1><<<MTOT/64, 256, 0, stream>>>(xb,   WvP,  b_v,    nullptr, nullptr, vT, nullptr);
    gemm64<128,256,2><<<MTOT/64, 256, 0, stream>>>(emab, WrstP,b_reset,nullptr, nullptr, rstb, nullptr);

    attn_kernel<<<dim3(80, BB), 256, 0, stream>>>(qb, kb, vT, btab, aob, part_o, part_ml);
    attn_combine<<<dim3(24, BB), 256, 0, stream>>>(part_o, part_ml, aob);

    final_mfma<<<MTOT/64, 256, 0, stream>>>(emab, aob, rstb, x, WhP, UhP, WuP, bh, b_update, out);
}

// Round 6
// 168.682 us; speedup vs baseline: 29.0493x; 1.2648x over previous
//
#include <hip/hip_runtime.h>
#include <hip/hip_bf16.h>
#include <math.h>

#define BB 8
#define LL 2048
#define DD 128
#define DQKN 64
#define DVN 256
#define MTOT (BB*LL)
#define SCALE 0.08838834764831845f  // 128^-0.5
#define LOG2E 1.4426950408889634f
#define QSCALE (SCALE*LOG2E)

#define CHUNK 32
#define NCH (LL/CHUNK)   // 64
#define CT 8             // KV tiles (of 64) per attn chunk-block

typedef __attribute__((ext_vector_type(4))) float f32x4;
typedef __attribute__((ext_vector_type(8))) short s16x8;

__device__ __forceinline__ float sigmoidf_(float x){ return 1.f/(1.f+__expf(-x)); }
__device__ __forceinline__ float siluf_(float x){ return x/(1.f+__expf(-x)); }
__device__ __forceinline__ __hip_bfloat16 f2bf(float f){ return __float2bfloat16(f); }
__device__ __forceinline__ ushort f2bfu(float f){ __hip_bfloat16 h = __float2bfloat16(f); return *(const ushort*)&h; }
__device__ __forceinline__ float bf2f(ushort u){ union{unsigned i; float f;} v; v.i = ((unsigned)u)<<16; return v.f; }

// ---------------- fused: pack all weights + bias table (1 launch)
__global__ void pack_all(const float* __restrict__ Wqk, const float* __restrict__ Wv,
                         const float* __restrict__ Wrst, const float* __restrict__ Wu,
                         const float* __restrict__ Wh, const float* __restrict__ Uh,
                         const float* __restrict__ rel_bias,
                         __hip_bfloat16* __restrict__ WqkP, __hip_bfloat16* __restrict__ WvP,
                         __hip_bfloat16* __restrict__ WrstP, __hip_bfloat16* __restrict__ WuP,
                         __hip_bfloat16* __restrict__ WhP, __hip_bfloat16* __restrict__ UhP,
                         float* __restrict__ btab) {
    int blk = blockIdx.x;
    int l = threadIdx.x;  // 64
    if (blk == 272) {
        // bias table: btab[n] = rel_bias[bucket(n)] * sqrt(DQK) * LOG2E
        for (int n = l; n < LL; n += 64) {
            int bucket;
            if (n < 16) bucket = n;
            else {
                float v = logf((float)n * (1.0f/16.0f)) * (1.0f/logf(8.0f)) * 16.0f;
                bucket = 16 + (int)v;
                if (bucket > 31) bucket = 31;
            }
            btab[n] = rel_bias[bucket] * 8.0f * LOG2E;
        }
        return;
    }
    const float* W; __hip_bfloat16* Wp; int K, N;
    if (blk < 16)       { W=Wqk;  Wp=WqkP;  K=128; N=64; }
    else if (blk < 80)  { W=Wv;   Wp=WvP;   K=128; N=256; blk-=16; }
    else if (blk < 144) { W=Wrst; Wp=WrstP; K=128; N=256; blk-=80; }
    else if (blk < 176) { W=Wu;   Wp=WuP;   K=128; N=128; blk-=144; }
    else if (blk < 208) { W=Wh;   Wp=WhP;   K=128; N=128; blk-=176; }
    else                { W=Uh;   Wp=UhP;   K=256; N=128; blk-=208; }
    int k32 = blk % (K/32), n16 = blk / (K/32);
    int col = n16*16 + (l & 15);
    int krow = k32*32 + (l >> 4)*8;
    ushort tmp[8];
    #pragma unroll
    for (int j = 0; j < 8; ++j) tmp[j] = f2bfu(W[(size_t)(krow + j)*N + col]);
    *reinterpret_cast<uint4*>(Wp + ((size_t)(blockIdx.x >= 208 ? blk : blk)*0 + ((size_t)blk*64 + l))*8) = *reinterpret_cast<uint4*>(tmp);
}

// ---------------- EMA chunked scan
__global__ __launch_bounds__(256) void ema_scanA(const float* __restrict__ x,
                                                 const float* __restrict__ alphas,
                                                 const float* __restrict__ damps,
                                                 float* __restrict__ sl) {
    int tid = blockIdx.x * 256 + threadIdx.x;   // 65536
    int d = tid & 127;
    int c = (tid >> 7) & (NCH - 1);
    int b = tid >> 13;
    float u[16], r[16];
    #pragma unroll
    for (int h = 0; h < 16; ++h) {
        float a = sigmoidf_(alphas[h]);
        r[h] = (1.f - a) * sigmoidf_(damps[h]);
        u[h] = 0.f;
    }
    const float* xp = x + ((size_t)b * LL + c * CHUNK) * DD + d;
    #pragma unroll 4
    for (int i = 0; i < CHUNK; ++i) {
        float xv = xp[(size_t)i * DD];
        #pragma unroll
        for (int h = 0; h < 16; ++h) u[h] = fmaf(r[h], u[h], xv);
    }
    float* slp = sl + ((size_t)b * NCH + c) * 16 * DD + d;
    #pragma unroll
    for (int h = 0; h < 16; ++h) slp[(size_t)h * DD] = u[h];
}

__global__ __launch_bounds__(256) void ema_scanB(const float* __restrict__ alphas,
                                                 const float* __restrict__ damps,
                                                 const float* __restrict__ sl,
                                                 float* __restrict__ carry) {
    int tid = blockIdx.x * 256 + threadIdx.x;   // 16384
    int d = tid & 127;
    int h = (tid >> 7) & 15;
    int b = tid >> 11;
    float a = sigmoidf_(alphas[h]);
    float r = (1.f - a) * sigmoidf_(damps[h]);
    float rC = r;
    #pragma unroll
    for (int q = 0; q < 5; ++q) rC *= rC;       // r^32
    const float* slp = sl + ((size_t)b * NCH * 16 + h) * DD + d;
    float* cp = carry + ((size_t)b * NCH * 16 + h) * DD + d;
    float u = 0.f;
    for (int c = 0; c < NCH; ++c) {
        cp[(size_t)c * 16 * DD] = u;
        u = slp[(size_t)c * 16 * DD] + rC * u;
    }
}

__global__ __launch_bounds__(256) void ema_scanC(const float* __restrict__ x,
                                                 const float* __restrict__ expansion,
                                                 const float* __restrict__ reduction,
                                                 const float* __restrict__ alphas,
                                                 const float* __restrict__ damps,
                                                 const float* __restrict__ carry,
                                                 __hip_bfloat16* __restrict__ emab,
                                                 __hip_bfloat16* __restrict__ xb) {
    int tid = blockIdx.x * 256 + threadIdx.x;   // 65536
    int d = tid & 127;
    int c = (tid >> 7) & (NCH - 1);
    int b = tid >> 13;
    float u[16], r[16], we[16];
    #pragma unroll
    for (int h = 0; h < 16; ++h) {
        float a = sigmoidf_(alphas[h]);
        r[h] = (1.f - a) * sigmoidf_(damps[h]);
        we[h] = reduction[h * DD + d] * a * expansion[h * DD + d];
        u[h] = carry[((size_t)b * NCH + c) * 16 * DD + (size_t)h * DD + d];
    }
    const float* xp = x + ((size_t)b * LL + c * CHUNK) * DD + d;
    __hip_bfloat16* ep = emab + ((size_t)b * LL + c * CHUNK) * DD + d;
    __hip_bfloat16* xbp = xb + ((size_t)b * LL + c * CHUNK) * DD + d;
    #pragma unroll 4
    for (int i = 0; i < CHUNK; ++i) {
        float xv = xp[(size_t)i * DD];
        float acc = 0.f;
        #pragma unroll
        for (int h = 0; h < 16; ++h) {
            u[h] = fmaf(r[h], u[h], xv);
            acc = fmaf(we[h], u[h], acc);
        }
        ep[(size_t)i * DD] = f2bf(acc);
        xbp[(size_t)i * DD] = f2bf(xv);
    }
}

// ---------------- QK GEMM: qk = silu(ema@W_qk+b); q = (qk*g0+b0)*QSCALE (fold), k = qk*g1+b1
__global__ __launch_bounds__(256) void gemm_qk(const __hip_bfloat16* __restrict__ A,
        const __hip_bfloat16* __restrict__ Wp, const float* __restrict__ bias,
        const float* __restrict__ gamma, const float* __restrict__ beta,
        __hip_bfloat16* __restrict__ qb, __hip_bfloat16* __restrict__ kb) {
    __shared__ char AsB[64*256];
    const int row0 = blockIdx.x * 64;
    const int t = threadIdx.x, w = t>>6, lane = t&63, l16 = lane&15, l4 = lane>>4;
    #pragma unroll
    for (int p = 0; p < 4; ++p) {
        int idx = p*256 + t;
        int row = idx / 16, u = idx % 16;
        uint4 d = *reinterpret_cast<const uint4*>(A + (size_t)(row0+row)*DD + u*8);
        *reinterpret_cast<uint4*>(AsB + row*256 + ((u*16) ^ ((row&7)<<4))) = d;
    }
    __syncthreads();
    f32x4 acc[4];
    #pragma unroll
    for (int n = 0; n < 4; ++n) acc[n] = (f32x4){0.f,0.f,0.f,0.f};
    const int arow = w*16 + l16;
    #pragma unroll
    for (int k32 = 0; k32 < 4; ++k32) {
        s16x8 af = *reinterpret_cast<const s16x8*>(AsB + arow*256 + ((k32*64 + l4*16) ^ ((arow&7)<<4)));
        #pragma unroll
        for (int n = 0; n < 4; ++n) {
            s16x8 bfr = *reinterpret_cast<const s16x8*>(Wp + ((size_t)(n*4 + k32)*64 + lane)*8);
            acc[n] = __builtin_amdgcn_mfma_f32_16x16x32_bf16(af, bfr, acc[n], 0, 0, 0);
        }
    }
    #pragma unroll
    for (int n = 0; n < 4; ++n) {
        int col = n*16 + l16;
        float bb = bias[col];
        float g0 = gamma[col], g1 = gamma[DQKN + col];
        float be0 = beta[col], be1 = beta[DQKN + col];
        #pragma unroll
        for (int r = 0; r < 4; ++r) {
            int row = w*16 + l4*4 + r;
            float s = siluf_(acc[n][r] + bb);
            qb[(size_t)(row0+row)*DQKN + col] = f2bf((s*g0 + be0) * QSCALE);
            kb[(size_t)(row0+row)*DQKN + col] = f2bf(s*g1 + be1);
        }
    }
}

// ---------------- fused V+RST GEMM (grid.y: 0 = V->vT, 1 = RST row-major), N=256
__global__ __launch_bounds__(256) void gemm_vrst(const __hip_bfloat16* __restrict__ xb,
        const __hip_bfloat16* __restrict__ emab,
        const __hip_bfloat16* __restrict__ WvP, const __hip_bfloat16* __restrict__ WrstP,
        const float* __restrict__ b_v, const float* __restrict__ b_rst,
        __hip_bfloat16* __restrict__ vT, __hip_bfloat16* __restrict__ rstb) {
    __shared__ char AsB[64*256];
    const int mode = blockIdx.y;
    const __hip_bfloat16* A = mode ? emab : xb;
    const __hip_bfloat16* Wp = mode ? WrstP : WvP;
    const float* bias = mode ? b_rst : b_v;
    const int row0 = blockIdx.x * 64;
    const int t = threadIdx.x, w = t>>6, lane = t&63, l16 = lane&15, l4 = lane>>4;
    #pragma unroll
    for (int p = 0; p < 4; ++p) {
        int idx = p*256 + t;
        int row = idx / 16, u = idx % 16;
        uint4 d = *reinterpret_cast<const uint4*>(A + (size_t)(row0+row)*DD + u*8);
        *reinterpret_cast<uint4*>(AsB + row*256 + ((u*16) ^ ((row&7)<<4))) = d;
    }
    __syncthreads();
    f32x4 acc[16];
    #pragma unroll
    for (int n = 0; n < 16; ++n) acc[n] = (f32x4){0.f,0.f,0.f,0.f};
    const int arow = w*16 + l16;
    #pragma unroll
    for (int k32 = 0; k32 < 4; ++k32) {
        s16x8 af = *reinterpret_cast<const s16x8*>(AsB + arow*256 + ((k32*64 + l4*16) ^ ((arow&7)<<4)));
        #pragma unroll
        for (int n = 0; n < 16; ++n) {
            s16x8 bfr = *reinterpret_cast<const s16x8*>(Wp + ((size_t)(n*4 + k32)*64 + lane)*8);
            acc[n] = __builtin_amdgcn_mfma_f32_16x16x32_bf16(af, bfr, acc[n], 0, 0, 0);
        }
    }
    if (mode == 0) {
        int bb_i = row0 >> 11;
        int lpos0 = (row0 & 2047) + w*16 + l4*4;
        #pragma unroll
        for (int n = 0; n < 16; ++n) {
            int col = n*16 + l16;
            float bb = bias[col];
            ushort pk[4];
            #pragma unroll
            for (int r = 0; r < 4; ++r) pk[r] = f2bfu(siluf_(acc[n][r] + bb));
            *reinterpret_cast<ushort4*>(vT + ((size_t)bb_i*DVN + col)*LL + lpos0) = *reinterpret_cast<ushort4*>(pk);
        }
    } else {
        #pragma unroll
        for (int n = 0; n < 16; ++n) {
            int col = n*16 + l16;
            float bb = bias[col];
            #pragma unroll
            for (int r = 0; r < 4; ++r) {
                int row = w*16 + l4*4 + r;
                rstb[(size_t)(row0+row)*DVN + col] = f2bf(siluf_(acc[n][r] + bb));
            }
        }
    }
}

// ---------------- MFMA flash attention, split-KV, reg-prefetch, exp2 domain, bf16 partials
__global__ __launch_bounds__(256) void attn_kernel(
    const __hip_bfloat16* __restrict__ qg, const __hip_bfloat16* __restrict__ kg,
    const __hip_bfloat16* __restrict__ vTg, const float* __restrict__ btab,
    __hip_bfloat16* __restrict__ aob, __hip_bfloat16* __restrict__ part_o,
    float* __restrict__ part_ml) {
    __shared__ __hip_bfloat16 Ks[64 * 64];      // swizzled
    __shared__ __hip_bfloat16 Vs[256 * 64];     // vT tile, swizzled
    __shared__ __hip_bfloat16 Ps[4][16][72];
    __shared__ float btl[576];
    const int cid = 79 - (int)blockIdx.x;       // fat chunks launch first
    const int b = blockIdx.y;
    int ti, cch;
    if (cid < 8)       { ti = cid;                 cch = 0; }
    else if (cid < 24) { ti = 8  + ((cid-8)>>1);   cch = (cid-8)&1; }
    else if (cid < 48) { ti = 16 + (cid-24)/3;     cch = (cid-24)%3; }
    else               { ti = 24 + ((cid-48)>>2);  cch = (cid-48)&3; }
    const int i0 = ti * 64;
    const int jlo = cch * (CT*64);
    int jhi = jlo + CT*64; { int je = (ti+1)*64; if (jhi > je) jhi = je; }
    const int nt = (jhi - jlo) >> 6;
    const int t = threadIdx.x;
    const int w = t >> 6, lane = t & 63;
    const int l16 = lane & 15, l4 = lane >> 4;
    char* KsB = (char*)Ks;
    char* VsB = (char*)Vs;

    int dmin = i0 - jhi + 1; if (dmin < 0) dmin = 0;
    const int cnt = (i0 + 63 - jlo) - dmin + 1;
    for (int idx = t; idx < cnt; idx += 256) btl[idx] = btab[dmin + idx];

    const int irow = i0 + w * 16 + l16;
    s16x8 qf[2];
    qf[0] = *reinterpret_cast<const s16x8*>(qg + ((size_t)b * LL + irow) * DQKN + l4 * 8);
    qf[1] = *reinterpret_cast<const s16x8*>(qg + ((size_t)b * LL + irow) * DQKN + 32 + l4 * 8);

    f32x4 o[16];
    #pragma unroll
    for (int n16 = 0; n16 < 16; ++n16) o[n16] = (f32x4){0.f, 0.f, 0.f, 0.f};
    float m[4] = {-1e30f, -1e30f, -1e30f, -1e30f};
    float l[4] = {0.f, 0.f, 0.f, 0.f};

    uint4 kreg[2], vreg[8];
    #define LOADK(J0) { _Pragma("unroll") for (int p = 0; p < 2; ++p) { \
        int idx = p*256 + t; int row = idx >> 3, c16 = idx & 7; \
        kreg[p] = *reinterpret_cast<const uint4*>(kg + ((size_t)b * LL + (J0) + row) * DQKN + c16 * 8); } }
    #define LOADV(J0) { _Pragma("unroll") for (int p = 0; p < 8; ++p) { \
        int idx = p*256 + t; int n = idx >> 3, c16 = idx & 7; \
        vreg[p] = *reinterpret_cast<const uint4*>(vTg + ((size_t)b * DVN + n) * LL + (J0) + c16 * 8); } }
    #define WRITEK() { _Pragma("unroll") for (int p = 0; p < 2; ++p) { \
        int idx = p*256 + t; int row = idx >> 3, c16 = idx & 7; \
        *reinterpret_cast<uint4*>(KsB + row * 128 + ((c16 * 16) ^ ((row & 7) << 4))) = kreg[p]; } }
    #define WRITEV() { _Pragma("unroll") for (int p = 0; p < 8; ++p) { \
        int idx = p*256 + t; int n = idx >> 3, c16 = idx & 7; \
        *reinterpret_cast<uint4*>(VsB + n * 128 + ((c16 * 16) ^ ((n & 7) << 4))) = vreg[p]; } }

    LOADK(jlo); LOADV(jlo);

    for (int tt = 0; tt < nt; ++tt) {
        const int j0 = jlo + tt * 64;
        __syncthreads();                   // prior compute done reading LDS
        WRITEK(); WRITEV();                // regs -> LDS (waits vmcnt inside)
        __syncthreads();
        if (tt + 1 < nt) { LOADK(j0 + 64); LOADV(j0 + 64); }  // async, hides under compute
        // QK^T (q pre-scaled by SCALE*LOG2E)
        f32x4 s[4];
        #pragma unroll
        for (int t16 = 0; t16 < 4; ++t16) s[t16] = (f32x4){0.f, 0.f, 0.f, 0.f};
        #pragma unroll
        for (int c = 0; c < 2; ++c) {
            #pragma unroll
            for (int t16 = 0; t16 < 4; ++t16) {
                int j = t16 * 16 + l16;
                s16x8 kf = *reinterpret_cast<const s16x8*>(KsB + j * 128 + ((c * 64 + l4 * 16) ^ ((j & 7) << 4)));
                s[t16] = __builtin_amdgcn_mfma_f32_16x16x32_bf16(qf[c], kf, s[t16], 0, 0, 0);
            }
        }
        // bias + mask (log2 domain), row stats
        float sv[4][4];
        float rmax[4] = {-1e30f, -1e30f, -1e30f, -1e30f};
        #pragma unroll
        for (int t16 = 0; t16 < 4; ++t16) {
            #pragma unroll
            for (int r = 0; r < 4; ++r) {
                int row = l4 * 4 + r;
                int dlt = (i0 + w * 16 + row) - (j0 + t16 * 16 + l16);
                int bi = dlt - dmin; if (bi < 0) bi = 0;
                float bv = btl[bi];
                float val = (dlt >= 0) ? (s[t16][r] + bv) : -1e30f;
                sv[t16][r] = val;
                rmax[r] = fmaxf(rmax[r], val);
            }
        }
        #pragma unroll
        for (int off = 1; off < 16; off <<= 1) {
            #pragma unroll
            for (int r = 0; r < 4; ++r) rmax[r] = fmaxf(rmax[r], __shfl_xor(rmax[r], off));
        }
        // exact skip-rescale: only rescale when the max actually grows
        bool need = (rmax[0] > m[0]) || (rmax[1] > m[1]) || (rmax[2] > m[2]) || (rmax[3] > m[3]);
        if (__any(need)) {
            float alpha[4];
            #pragma unroll
            for (int r = 0; r < 4; ++r) {
                float mn = fmaxf(m[r], rmax[r]);
                alpha[r] = exp2f(m[r] - mn);
                m[r] = mn;
                l[r] *= alpha[r];
            }
            #pragma unroll
            for (int n16 = 0; n16 < 16; ++n16) {
                #pragma unroll
                for (int r = 0; r < 4; ++r) o[n16][r] *= alpha[r];
            }
        }
        float psum[4] = {0.f, 0.f, 0.f, 0.f};
        #pragma unroll
        for (int t16 = 0; t16 < 4; ++t16) {
            #pragma unroll
            for (int r = 0; r < 4; ++r) {
                float p = exp2f(sv[t16][r] - m[r]);
                psum[r] += p;
                Ps[w][l4 * 4 + r][t16 * 16 + l16] = f2bf(p);
            }
        }
        #pragma unroll
        for (int off = 1; off < 16; off <<= 1) {
            #pragma unroll
            for (int r = 0; r < 4; ++r) psum[r] += __shfl_xor(psum[r], off);
        }
        #pragma unroll
        for (int r = 0; r < 4; ++r) l[r] += psum[r];
        // PV (Ps wave-private)
        #pragma unroll
        for (int c = 0; c < 2; ++c) {
            s16x8 pf = *reinterpret_cast<const s16x8*>(&Ps[w][l16][c * 32 + l4 * 8]);
            #pragma unroll
            for (int n16 = 0; n16 < 16; ++n16) {
                int n = n16 * 16 + l16;
                s16x8 vf = *reinterpret_cast<const s16x8*>(VsB + n * 128 + ((c * 64 + l4 * 16) ^ ((n & 7) << 4)));
                o[n16] = __builtin_amdgcn_mfma_f32_16x16x32_bf16(pf, vf, o[n16], 0, 0, 0);
            }
        }
    }
    if (ti < 8) {
        float invl[4];
        #pragma unroll
        for (int r = 0; r < 4; ++r) invl[r] = 1.f / l[r];
        #pragma unroll
        for (int n16 = 0; n16 < 16; ++n16) {
            #pragma unroll
            for (int r = 0; r < 4; ++r) {
                aob[((size_t)b * LL + i0 + w * 16 + l4 * 4 + r) * DVN + n16 * 16 + l16] = f2bf(o[n16][r] * invl[r]);
            }
        }
    } else {
        const size_t slot = (size_t)b * 80 + cid;
        __hip_bfloat16* po = part_o + slot * (64 * 256);
        #pragma unroll
        for (int n16 = 0; n16 < 16; ++n16) {
            #pragma unroll
            for (int r = 0; r < 4; ++r)
                po[(size_t)(w * 16 + l4 * 4 + r) * 256 + n16 * 16 + l16] = f2bf(o[n16][r]);
        }
        if (l16 == 0) {
            #pragma unroll
            for (int r = 0; r < 4; ++r) {
                int row = w * 16 + l4 * 4 + r;
                part_ml[slot * 128 + row * 2]     = m[r];
                part_ml[slot * 128 + row * 2 + 1] = l[r];
            }
        }
    }
    #undef LOADK
    #undef LOADV
    #undef WRITEK
    #undef WRITEV
}

// ---------------- combine partials (ti >= 8), bf16 partials, exp2 domain
__global__ __launch_bounds__(256) void attn_combine(const __hip_bfloat16* __restrict__ part_o,
                                                    const float* __restrict__ part_ml,
                                                    __hip_bfloat16* __restrict__ aob) {
    const int tix = blockIdx.x;       // 0..23 -> ti = 8+tix
    const int b = blockIdx.y;
    const int ti = 8 + tix;
    int nc, cid0;
    if (ti < 16)      { nc = 2; cid0 = 8  + (ti-8)*2; }
    else if (ti < 24) { nc = 3; cid0 = 24 + (ti-16)*3; }
    else              { nc = 4; cid0 = 48 + (ti-24)*4; }
    const size_t slot0 = (size_t)b * 80 + cid0;
    __shared__ float sW[4][64];
    __shared__ float sinvL[64];
    const int t = threadIdx.x;
    if (t < 64) {
        float mm[4], ll[4], M = -1e30f;
        for (int c = 0; c < nc; ++c) {
            mm[c] = part_ml[(slot0 + c) * 128 + t * 2];
            ll[c] = part_ml[(slot0 + c) * 128 + t * 2 + 1];
            M = fmaxf(M, mm[c]);
        }
        float L = 0.f;
        for (int c = 0; c < nc; ++c) {
            float wv = exp2f(mm[c] - M);
            sW[c][t] = wv;
            L += wv * ll[c];
        }
        sinvL[t] = 1.f / L;
    }
    __syncthreads();
    const int i0 = ti * 64;
    #pragma unroll
    for (int it = 0; it < 8; ++it) {
        int idx = it * 256 + t;         // 8-bf16 units over 64x256
        int row = idx >> 5, c8 = idx & 31;
        float acc[8] = {0.f,0.f,0.f,0.f,0.f,0.f,0.f,0.f};
        for (int c = 0; c < nc; ++c) {
            float wv = sW[c][row];
            uint4 d = *reinterpret_cast<const uint4*>(part_o + (slot0 + c) * (size_t)(64*256) + row * 256 + c8 * 8);
            const ushort* pp = (const ushort*)&d;
            #pragma unroll
            for (int j = 0; j < 8; ++j) acc[j] = fmaf(wv, bf2f(pp[j]), acc[j]);
        }
        float il = sinvL[row];
        ushort pk[8];
        #pragma unroll
        for (int j = 0; j < 8; ++j) pk[j] = f2bfu(acc[j] * il);
        *reinterpret_cast<uint4*>(aob + ((size_t)b * LL + i0 + row) * DVN + c8 * 8) = *reinterpret_cast<uint4*>(pk);
    }
}

// ---------------- fused final, split by column half (grid.y)
__global__ __launch_bounds__(256) void final_mfma(
        const __hip_bfloat16* __restrict__ emab, const __hip_bfloat16* __restrict__ aob,
        const __hip_bfloat16* __restrict__ rstb, const float* __restrict__ x,
        const __hip_bfloat16* __restrict__ WhP, const __hip_bfloat16* __restrict__ UhP,
        const __hip_bfloat16* __restrict__ WuP, const float* __restrict__ bh,
        const float* __restrict__ bu, float* __restrict__ out) {
    __shared__ char As1[64*256];   // ema tile, K=128
    __shared__ char As2[64*512];   // gated tile, K=256
    const int row0 = blockIdx.x * 64;
    const int ch = blockIdx.y;     // column half: cols [ch*64, ch*64+64)
    const int t = threadIdx.x, w = t>>6, lane = t&63, l16 = lane&15, l4 = lane>>4;
    #pragma unroll
    for (int p = 0; p < 4; ++p) {
        int idx = p*256 + t;
        int row = idx / 16, u = idx % 16;
        uint4 d = *reinterpret_cast<const uint4*>(emab + (size_t)(row0+row)*DD + u*8);
        *reinterpret_cast<uint4*>(As1 + row*256 + ((u*16) ^ ((row&7)<<4))) = d;
    }
    #pragma unroll
    for (int p = 0; p < 8; ++p) {
        int idx = p*256 + t;
        int row = idx / 32, u = idx % 32;
        uint4 da = *reinterpret_cast<const uint4*>(aob + (size_t)(row0+row)*DVN + u*8);
        uint4 dr = *reinterpret_cast<const uint4*>(rstb + (size_t)(row0+row)*DVN + u*8);
        const ushort* pa = (const ushort*)&da;
        const ushort* pr = (const ushort*)&dr;
        ushort g[8];
        #pragma unroll
        for (int j = 0; j < 8; ++j) g[j] = f2bfu(bf2f(pa[j]) * bf2f(pr[j]));
        *reinterpret_cast<uint4*>(As2 + row*512 + ((u*16) ^ ((row&7)<<4))) = *reinterpret_cast<uint4*>(g);
    }
    __syncthreads();
    f32x4 acc1[4], acc2[4];
    #pragma unroll
    for (int n = 0; n < 4; ++n) { acc1[n] = (f32x4){0.f,0.f,0.f,0.f}; acc2[n] = (f32x4){0.f,0.f,0.f,0.f}; }
    const int arow = w*16 + l16;
    #pragma unroll
    for (int k32 = 0; k32 < 4; ++k32) {
        s16x8 af = *reinterpret_cast<const s16x8*>(As1 + arow*256 + ((k32*64 + l4*16) ^ ((arow&7)<<4)));
        #pragma unroll
        for (int n = 0; n < 4; ++n) {
            s16x8 bw = *reinterpret_cast<const s16x8*>(WhP + ((size_t)((ch*4+n)*4 + k32)*64 + lane)*8);
            acc1[n] = __builtin_amdgcn_mfma_f32_16x16x32_bf16(af, bw, acc1[n], 0, 0, 0);
            s16x8 bu2 = *reinterpret_cast<const s16x8*>(WuP + ((size_t)((ch*4+n)*4 + k32)*64 + lane)*8);
            acc2[n] = __builtin_amdgcn_mfma_f32_16x16x32_bf16(af, bu2, acc2[n], 0, 0, 0);
        }
    }
    #pragma unroll
    for (int k32 = 0; k32 < 8; ++k32) {
        s16x8 gf = *reinterpret_cast<const s16x8*>(As2 + arow*512 + ((k32*64 + l4*16) ^ ((arow&7)<<4)));
        #pragma unroll
        for (int n = 0; n < 4; ++n) {
            s16x8 bw = *reinterpret_cast<const s16x8*>(UhP + ((size_t)((ch*4+n)*8 + k32)*64 + lane)*8);
            acc1[n] = __builtin_amdgcn_mfma_f32_16x16x32_bf16(gf, bw, acc1[n], 0, 0, 0);
        }
    }
    #pragma unroll
    for (int n = 0; n < 4; ++n) {
        int col = ch*64 + n*16 + l16;
        float bbh = bh[col], bbu = bu[col];
        #pragma unroll
        for (int r = 0; r < 4; ++r) {
            int row = w*16 + l4*4 + r;
            size_t gidx = (size_t)(row0+row)*DD + col;
            float hh = siluf_(acc1[n][r] + bbh);
            float u = sigmoidf_(acc2[n][r] + bbu);
            float xv = x[gidx];
            out[gidx] = u*hh + (1.f-u)*xv;
        }
    }
}

extern "C" void kernel_launch(void* const* d_in, const int* in_sizes, int n_in,
                              void* d_out, int out_size, void* d_ws, size_t ws_size,
                              hipStream_t stream) {
    const float* x        = (const float*)d_in[0];
    const float* expansion= (const float*)d_in[1];
    const float* reduction= (const float*)d_in[2];
    const float* alphas   = (const float*)d_in[3];
    const float* damps    = (const float*)d_in[4];
    const float* rel_bias = (const float*)d_in[5];
    const float* W_qk     = (const float*)d_in[6];
    const float* b_qk     = (const float*)d_in[7];
    const float* gamma    = (const float*)d_in[8];
    const float* beta     = (const float*)d_in[9];
    const float* W_v      = (const float*)d_in[10];
    const float* b_v      = (const float*)d_in[11];
    const float* W_reset  = (const float*)d_in[12];
    const float* b_reset  = (const float*)d_in[13];
    const float* W_update = (const float*)d_in[14];
    const float* b_update = (const float*)d_in[15];
    const float* Wh       = (const float*)d_in[16];
    const float* Uh       = (const float*)d_in[17];
    const float* bh       = (const float*)d_in[18];
    float* out = (float*)d_out;

    char* base = (char*)d_ws;
    __hip_bfloat16* emab = (__hip_bfloat16*)base;  base += (size_t)MTOT * DD * 2;
    __hip_bfloat16* xb   = (__hip_bfloat16*)base;  base += (size_t)MTOT * DD * 2;
    __hip_bfloat16* qb   = (__hip_bfloat16*)base;  base += (size_t)MTOT * DQKN * 2;
    __hip_bfloat16* kb   = (__hip_bfloat16*)base;  base += (size_t)MTOT * DQKN * 2;
    __hip_bfloat16* vT   = (__hip_bfloat16*)base;  base += (size_t)MTOT * DVN * 2;
    __hip_bfloat16* rstb = (__hip_bfloat16*)base;  base += (size_t)MTOT * DVN * 2;
    __hip_bfloat16* aob  = (__hip_bfloat16*)base;  base += (size_t)MTOT * DVN * 2;
    float* btab  = (float*)base;                   base += (size_t)LL * 4;
    float* sl    = (float*)base;                   base += (size_t)BB * NCH * 16 * DD * 4;
    float* carry = (float*)base;                   base += (size_t)BB * NCH * 16 * DD * 4;
    __hip_bfloat16* WqkP = (__hip_bfloat16*)base;  base += (size_t)DD * DQKN * 2;
    __hip_bfloat16* WvP  = (__hip_bfloat16*)base;  base += (size_t)DD * DVN * 2;
    __hip_bfloat16* WrstP= (__hip_bfloat16*)base;  base += (size_t)DD * DVN * 2;
    __hip_bfloat16* WuP  = (__hip_bfloat16*)base;  base += (size_t)DD * DD * 2;
    __hip_bfloat16* WhP  = (__hip_bfloat16*)base;  base += (size_t)DD * DD * 2;
    __hip_bfloat16* UhP  = (__hip_bfloat16*)base;  base += (size_t)DVN * DD * 2;
    __hip_bfloat16* part_o = (__hip_bfloat16*)base; base += (size_t)BB * 80 * 64 * 256 * 2;
    float* part_ml = (float*)base;                 base += (size_t)BB * 80 * 128 * 4;

    pack_all<<<273, 64, 0, stream>>>(W_qk, W_v, W_reset, W_update, Wh, Uh, rel_bias,
                                     WqkP, WvP, WrstP, WuP, WhP, UhP, btab);

    ema_scanA<<<BB * NCH * DD / 256, 256, 0, stream>>>(x, alphas, damps, sl);
    ema_scanB<<<BB * 16 * DD / 256, 256, 0, stream>>>(alphas, damps, sl, carry);
    ema_scanC<<<BB * NCH * DD / 256, 256, 0, stream>>>(x, expansion, reduction, alphas, damps, carry, emab, xb);

    gemm_qk<<<MTOT/64, 256, 0, stream>>>(emab, WqkP, b_qk, gamma, beta, qb, kb);
    gemm_vrst<<<dim3(MTOT/64, 2), 256, 0, stream>>>(xb, emab, WvP, WrstP, b_v, b_reset, vT, rstb);

    attn_kernel<<<dim3(80, BB), 256, 0, stream>>>(qb, kb, vT, btab, aob, part_o, part_ml);
    attn_combine<<<dim3(24, BB), 256, 0, stream>>>(part_o, part_ml, aob);

    final_mfma<<<dim3(MTOT/64, 2), 256, 0, stream>>>(emab, aob, rstb, x, WhP, UhP, WuP, bh, b_update, out);
}

// Round 7
// 120.944 us; speedup vs baseline: 40.5157x; 1.3947x over previous
//
#include <hip/hip_runtime.h>
#include <hip/hip_bf16.h>
#include <math.h>

#define BB 8
#define LL 2048
#define DD 128
#define DQKN 64
#define DVN 256
#define MTOT (BB*LL)
#define SCALE 0.08838834764831845f  // 128^-0.5
#define LOG2E 1.4426950408889634f
#define QSCALE (SCALE*LOG2E)

#define CHUNK 32
#define NCH (LL/CHUNK)   // 64
#define CT 4             // KV tiles (of 64) per attn chunk-block
#define NCHK 144         // chunks per batch = sum_{g=0..7} 4*(g+1)

typedef __attribute__((ext_vector_type(4))) float f32x4;
typedef __attribute__((ext_vector_type(8))) short s16x8;

__device__ __forceinline__ float sigmoidf_(float x){ return 1.f/(1.f+__expf(-x)); }
__device__ __forceinline__ float siluf_(float x){ return x/(1.f+__expf(-x)); }
__device__ __forceinline__ __hip_bfloat16 f2bf(float f){ return __float2bfloat16(f); }
__device__ __forceinline__ ushort f2bfu(float f){ __hip_bfloat16 h = __float2bfloat16(f); return *(const ushort*)&h; }
__device__ __forceinline__ float bf2f(ushort u){ union{unsigned i; float f;} v; v.i = ((unsigned)u)<<16; return v.f; }

__device__ __forceinline__ void gl_lds16(const __hip_bfloat16* g, void* l) {
    __builtin_amdgcn_global_load_lds(
        (const __attribute__((address_space(1))) void*)g,
        (__attribute__((address_space(3))) void*)l, 16, 0, 0);
}

// ---------------- fused: pack all weights + bias table (1 launch)
__global__ void pack_all(const float* __restrict__ Wqk, const float* __restrict__ Wv,
                         const float* __restrict__ Wrst, const float* __restrict__ Wu,
                         const float* __restrict__ Wh, const float* __restrict__ Uh,
                         const float* __restrict__ rel_bias,
                         __hip_bfloat16* __restrict__ WqkP, __hip_bfloat16* __restrict__ WvP,
                         __hip_bfloat16* __restrict__ WrstP, __hip_bfloat16* __restrict__ WuP,
                         __hip_bfloat16* __restrict__ WhP, __hip_bfloat16* __restrict__ UhP,
                         float* __restrict__ btab) {
    int blk = blockIdx.x;
    int l = threadIdx.x;  // 64
    if (blk == 272) {
        for (int n = l; n < LL; n += 64) {
            int bucket;
            if (n < 16) bucket = n;
            else {
                float v = logf((float)n * (1.0f/16.0f)) * (1.0f/logf(8.0f)) * 16.0f;
                bucket = 16 + (int)v;
                if (bucket > 31) bucket = 31;
            }
            btab[n] = rel_bias[bucket] * 8.0f * LOG2E;
        }
        return;
    }
    const float* W; __hip_bfloat16* Wp; int K, N;
    if (blk < 16)       { W=Wqk;  Wp=WqkP;  K=128; N=64; }
    else if (blk < 80)  { W=Wv;   Wp=WvP;   K=128; N=256; blk-=16; }
    else if (blk < 144) { W=Wrst; Wp=WrstP; K=128; N=256; blk-=80; }
    else if (blk < 176) { W=Wu;   Wp=WuP;   K=128; N=128; blk-=144; }
    else if (blk < 208) { W=Wh;   Wp=WhP;   K=128; N=128; blk-=176; }
    else                { W=Uh;   Wp=UhP;   K=256; N=128; blk-=208; }
    int k32 = blk % (K/32), n16 = blk / (K/32);
    int col = n16*16 + (l & 15);
    int krow = k32*32 + (l >> 4)*8;
    ushort tmp[8];
    #pragma unroll
    for (int j = 0; j < 8; ++j) tmp[j] = f2bfu(W[(size_t)(krow + j)*N + col]);
    *reinterpret_cast<uint4*>(Wp + ((size_t)blk*64 + l)*8) = *reinterpret_cast<uint4*>(tmp);
}

// ---------------- EMA chunked scan
__global__ __launch_bounds__(256) void ema_scanA(const float* __restrict__ x,
                                                 const float* __restrict__ alphas,
                                                 const float* __restrict__ damps,
                                                 float* __restrict__ sl) {
    int tid = blockIdx.x * 256 + threadIdx.x;   // 65536
    int d = tid & 127;
    int c = (tid >> 7) & (NCH - 1);
    int b = tid >> 13;
    float u[16], r[16];
    #pragma unroll
    for (int h = 0; h < 16; ++h) {
        float a = sigmoidf_(alphas[h]);
        r[h] = (1.f - a) * sigmoidf_(damps[h]);
        u[h] = 0.f;
    }
    const float* xp = x + ((size_t)b * LL + c * CHUNK) * DD + d;
    #pragma unroll 4
    for (int i = 0; i < CHUNK; ++i) {
        float xv = xp[(size_t)i * DD];
        #pragma unroll
        for (int h = 0; h < 16; ++h) u[h] = fmaf(r[h], u[h], xv);
    }
    float* slp = sl + ((size_t)b * NCH + c) * 16 * DD + d;
    #pragma unroll
    for (int h = 0; h < 16; ++h) slp[(size_t)h * DD] = u[h];
}

__global__ __launch_bounds__(256) void ema_scanB(const float* __restrict__ alphas,
                                                 const float* __restrict__ damps,
                                                 const float* __restrict__ sl,
                                                 float* __restrict__ carry) {
    int tid = blockIdx.x * 256 + threadIdx.x;   // 16384
    int d = tid & 127;
    int h = (tid >> 7) & 15;
    int b = tid >> 11;
    float a = sigmoidf_(alphas[h]);
    float r = (1.f - a) * sigmoidf_(damps[h]);
    float rC = r;
    #pragma unroll
    for (int q = 0; q < 5; ++q) rC *= rC;       // r^32
    const float* slp = sl + ((size_t)b * NCH * 16 + h) * DD + d;
    float* cp = carry + ((size_t)b * NCH * 16 + h) * DD + d;
    float u = 0.f;
    for (int c = 0; c < NCH; ++c) {
        cp[(size_t)c * 16 * DD] = u;
        u = slp[(size_t)c * 16 * DD] + rC * u;
    }
}

__global__ __launch_bounds__(256) void ema_scanC(const float* __restrict__ x,
                                                 const float* __restrict__ expansion,
                                                 const float* __restrict__ reduction,
                                                 const float* __restrict__ alphas,
                                                 const float* __restrict__ damps,
                                                 const float* __restrict__ carry,
                                                 __hip_bfloat16* __restrict__ emab,
                                                 __hip_bfloat16* __restrict__ xb) {
    int tid = blockIdx.x * 256 + threadIdx.x;   // 65536
    int d = tid & 127;
    int c = (tid >> 7) & (NCH - 1);
    int b = tid >> 13;
    float u[16], r[16], we[16];
    #pragma unroll
    for (int h = 0; h < 16; ++h) {
        float a = sigmoidf_(alphas[h]);
        r[h] = (1.f - a) * sigmoidf_(damps[h]);
        we[h] = reduction[h * DD + d] * a * expansion[h * DD + d];
        u[h] = carry[((size_t)b * NCH + c) * 16 * DD + (size_t)h * DD + d];
    }
    const float* xp = x + ((size_t)b * LL + c * CHUNK) * DD + d;
    __hip_bfloat16* ep = emab + ((size_t)b * LL + c * CHUNK) * DD + d;
    __hip_bfloat16* xbp = xb + ((size_t)b * LL + c * CHUNK) * DD + d;
    #pragma unroll 4
    for (int i = 0; i < CHUNK; ++i) {
        float xv = xp[(size_t)i * DD];
        float acc = 0.f;
        #pragma unroll
        for (int h = 0; h < 16; ++h) {
            u[h] = fmaf(r[h], u[h], xv);
            acc = fmaf(we[h], u[h], acc);
        }
        ep[(size_t)i * DD] = f2bf(acc);
        xbp[(size_t)i * DD] = f2bf(xv);
    }
}

// ---------------- QK GEMM: qk = silu(ema@W_qk+b); q=(qk*g0+b0)*QSCALE, k=qk*g1+b1
__global__ __launch_bounds__(256) void gemm_qk(const __hip_bfloat16* __restrict__ A,
        const __hip_bfloat16* __restrict__ Wp, const float* __restrict__ bias,
        const float* __restrict__ gamma, const float* __restrict__ beta,
        __hip_bfloat16* __restrict__ qb, __hip_bfloat16* __restrict__ kb) {
    __shared__ char AsB[64*256];
    const int row0 = blockIdx.x * 64;
    const int t = threadIdx.x, w = t>>6, lane = t&63, l16 = lane&15, l4 = lane>>4;
    #pragma unroll
    for (int p = 0; p < 4; ++p) {
        int idx = p*256 + t;
        int row = idx / 16, u = idx % 16;
        uint4 d = *reinterpret_cast<const uint4*>(A + (size_t)(row0+row)*DD + u*8);
        *reinterpret_cast<uint4*>(AsB + row*256 + ((u*16) ^ ((row&7)<<4))) = d;
    }
    __syncthreads();
    f32x4 acc[4];
    #pragma unroll
    for (int n = 0; n < 4; ++n) acc[n] = (f32x4){0.f,0.f,0.f,0.f};
    const int arow = w*16 + l16;
    #pragma unroll
    for (int k32 = 0; k32 < 4; ++k32) {
        s16x8 af = *reinterpret_cast<const s16x8*>(AsB + arow*256 + ((k32*64 + l4*16) ^ ((arow&7)<<4)));
        #pragma unroll
        for (int n = 0; n < 4; ++n) {
            s16x8 bfr = *reinterpret_cast<const s16x8*>(Wp + ((size_t)(n*4 + k32)*64 + lane)*8);
            acc[n] = __builtin_amdgcn_mfma_f32_16x16x32_bf16(af, bfr, acc[n], 0, 0, 0);
        }
    }
    #pragma unroll
    for (int n = 0; n < 4; ++n) {
        int col = n*16 + l16;
        float bb = bias[col];
        float g0 = gamma[col], g1 = gamma[DQKN + col];
        float be0 = beta[col], be1 = beta[DQKN + col];
        #pragma unroll
        for (int r = 0; r < 4; ++r) {
            int row = w*16 + l4*4 + r;
            float s = siluf_(acc[n][r] + bb);
            qb[(size_t)(row0+row)*DQKN + col] = f2bf((s*g0 + be0) * QSCALE);
            kb[(size_t)(row0+row)*DQKN + col] = f2bf(s*g1 + be1);
        }
    }
}

// ---------------- fused V+RST GEMM (grid.y: 0 = V->vT, 1 = RST row-major), N=256
__global__ __launch_bounds__(256) void gemm_vrst(const __hip_bfloat16* __restrict__ xb,
        const __hip_bfloat16* __restrict__ emab,
        const __hip_bfloat16* __restrict__ WvP, const __hip_bfloat16* __restrict__ WrstP,
        const float* __restrict__ b_v, const float* __restrict__ b_rst,
        __hip_bfloat16* __restrict__ vT, __hip_bfloat16* __restrict__ rstb) {
    __shared__ char AsB[64*256];
    const int mode = blockIdx.y;
    const __hip_bfloat16* A = mode ? emab : xb;
    const __hip_bfloat16* Wp = mode ? WrstP : WvP;
    const float* bias = mode ? b_rst : b_v;
    const int row0 = blockIdx.x * 64;
    const int t = threadIdx.x, w = t>>6, lane = t&63, l16 = lane&15, l4 = lane>>4;
    #pragma unroll
    for (int p = 0; p < 4; ++p) {
        int idx = p*256 + t;
        int row = idx / 16, u = idx % 16;
        uint4 d = *reinterpret_cast<const uint4*>(A + (size_t)(row0+row)*DD + u*8);
        *reinterpret_cast<uint4*>(AsB + row*256 + ((u*16) ^ ((row&7)<<4))) = d;
    }
    __syncthreads();
    f32x4 acc[16];
    #pragma unroll
    for (int n = 0; n < 16; ++n) acc[n] = (f32x4){0.f,0.f,0.f,0.f};
    const int arow = w*16 + l16;
    #pragma unroll
    for (int k32 = 0; k32 < 4; ++k32) {
        s16x8 af = *reinterpret_cast<const s16x8*>(AsB + arow*256 + ((k32*64 + l4*16) ^ ((arow&7)<<4)));
        #pragma unroll
        for (int n = 0; n < 16; ++n) {
            s16x8 bfr = *reinterpret_cast<const s16x8*>(Wp + ((size_t)(n*4 + k32)*64 + lane)*8);
            acc[n] = __builtin_amdgcn_mfma_f32_16x16x32_bf16(af, bfr, acc[n], 0, 0, 0);
        }
    }
    if (mode == 0) {
        int bb_i = row0 >> 11;
        int lpos0 = (row0 & 2047) + w*16 + l4*4;
        #pragma unroll
        for (int n = 0; n < 16; ++n) {
            int col = n*16 + l16;
            float bb = bias[col];
            ushort pk[4];
            #pragma unroll
            for (int r = 0; r < 4; ++r) pk[r] = f2bfu(siluf_(acc[n][r] + bb));
            *reinterpret_cast<ushort4*>(vT + ((size_t)bb_i*DVN + col)*LL + lpos0) = *reinterpret_cast<ushort4*>(pk);
        }
    } else {
        #pragma unroll
        for (int n = 0; n < 16; ++n) {
            int col = n*16 + l16;
            float bb = bias[col];
            #pragma unroll
            for (int r = 0; r < 4; ++r) {
                int row = w*16 + l4*4 + r;
                rstb[(size_t)(row0+row)*DVN + col] = f2bf(siluf_(acc[n][r] + bb));
            }
        }
    }
}

// ---------------- MFMA flash attention, split-KV CT=4, global_load_lds staging
__global__ __launch_bounds__(256) void attn_kernel(
    const __hip_bfloat16* __restrict__ qg, const __hip_bfloat16* __restrict__ kg,
    const __hip_bfloat16* __restrict__ vTg, const float* __restrict__ btab,
    __hip_bfloat16* __restrict__ aob, __hip_bfloat16* __restrict__ part_o,
    float* __restrict__ part_ml) {
    __shared__ __hip_bfloat16 Ks[64 * 64];      // linear fill; swizzle folded into global src
    __shared__ __hip_bfloat16 Vs[256 * 64];
    __shared__ __hip_bfloat16 Ps[4][16][72];
    __shared__ float btl[320];
    const int cid = NCHK - 1 - (int)blockIdx.x; // big groups first
    const int b = blockIdx.y;
    int g = 0;
    while (cid >= 2*(g+1)*(g+2)) ++g;           // group = ti>>2
    const int rel = cid - 2*g*(g+1);
    const int ti = 4*g + rel/(g+1);
    const int cch = rel % (g+1);
    const int i0 = ti * 64;
    const int jlo = cch * (CT*64);
    int jhi = jlo + CT*64; { int je = (ti+1)*64; if (jhi > je) jhi = je; }
    const int nt = (jhi - jlo) >> 6;
    const int t = threadIdx.x;
    const int w = t >> 6, lane = t & 63;
    const int l16 = lane & 15, l4 = lane >> 4;
    char* KsB = (char*)Ks;
    char* VsB = (char*)Vs;

    int dmin = i0 - jhi + 1; if (dmin < 0) dmin = 0;
    const int cnt = (i0 + 63 - jlo) - dmin + 1;
    for (int idx = t; idx < cnt; idx += 256) btl[idx] = btab[dmin + idx];

    const int irow = i0 + w * 16 + l16;
    s16x8 qf[2];
    qf[0] = *reinterpret_cast<const s16x8*>(qg + ((size_t)b * LL + irow) * DQKN + l4 * 8);
    qf[1] = *reinterpret_cast<const s16x8*>(qg + ((size_t)b * LL + irow) * DQKN + 32 + l4 * 8);

    f32x4 o[16];
    #pragma unroll
    for (int n16 = 0; n16 < 16; ++n16) o[n16] = (f32x4){0.f, 0.f, 0.f, 0.f};
    float m[4] = {-1e30f, -1e30f, -1e30f, -1e30f};
    float l[4] = {0.f, 0.f, 0.f, 0.f};

    for (int tt = 0; tt < nt; ++tt) {
        const int j0 = jlo + tt * 64;
        __syncthreads();       // done reading previous tile
        // stage K: 512 16B-units, linear LDS, swizzled global src (c16 = u ^ (row&7))
        #pragma unroll
        for (int i = 0; i < 2; ++i) {
            int base = w * 128 + i * 64;
            int idx = base + lane;
            int row = idx >> 3;
            int c16 = (idx & 7) ^ (row & 7);
            gl_lds16(kg + ((size_t)b * LL + j0 + row) * DQKN + c16 * 8, KsB + base * 16);
        }
        // stage V^T: 2048 units
        #pragma unroll
        for (int i = 0; i < 8; ++i) {
            int base = w * 512 + i * 64;
            int idx = base + lane;
            int n = idx >> 3;
            int c16 = (idx & 7) ^ (n & 7);
            gl_lds16(vTg + ((size_t)b * DVN + n) * LL + j0 + c16 * 8, VsB + base * 16);
        }
        __syncthreads();       // drains vmcnt; tile visible
        // QK^T (q pre-scaled by SCALE*LOG2E)
        f32x4 s[4];
        #pragma unroll
        for (int t16 = 0; t16 < 4; ++t16) s[t16] = (f32x4){0.f, 0.f, 0.f, 0.f};
        #pragma unroll
        for (int c = 0; c < 2; ++c) {
            #pragma unroll
            for (int t16 = 0; t16 < 4; ++t16) {
                int j = t16 * 16 + l16;
                s16x8 kf = *reinterpret_cast<const s16x8*>(KsB + j * 128 + ((c * 64 + l4 * 16) ^ ((j & 7) << 4)));
                s[t16] = __builtin_amdgcn_mfma_f32_16x16x32_bf16(qf[c], kf, s[t16], 0, 0, 0);
            }
        }
        float sv[4][4];
        float rmax[4] = {-1e30f, -1e30f, -1e30f, -1e30f};
        #pragma unroll
        for (int t16 = 0; t16 < 4; ++t16) {
            #pragma unroll
            for (int r = 0; r < 4; ++r) {
                int row = l4 * 4 + r;
                int dlt = (i0 + w * 16 + row) - (j0 + t16 * 16 + l16);
                int bi = dlt - dmin; if (bi < 0) bi = 0;
                float bv = btl[bi];
                float val = (dlt >= 0) ? (s[t16][r] + bv) : -1e30f;
                sv[t16][r] = val;
                rmax[r] = fmaxf(rmax[r], val);
            }
        }
        #pragma unroll
        for (int off = 1; off < 16; off <<= 1) {
            #pragma unroll
            for (int r = 0; r < 4; ++r) rmax[r] = fmaxf(rmax[r], __shfl_xor(rmax[r], off));
        }
        bool need = (rmax[0] > m[0]) || (rmax[1] > m[1]) || (rmax[2] > m[2]) || (rmax[3] > m[3]);
        if (__any(need)) {
            float alpha[4];
            #pragma unroll
            for (int r = 0; r < 4; ++r) {
                float mn = fmaxf(m[r], rmax[r]);
                alpha[r] = exp2f(m[r] - mn);
                m[r] = mn;
                l[r] *= alpha[r];
            }
            #pragma unroll
            for (int n16 = 0; n16 < 16; ++n16) {
                #pragma unroll
                for (int r = 0; r < 4; ++r) o[n16][r] *= alpha[r];
            }
        }
        float psum[4] = {0.f, 0.f, 0.f, 0.f};
        #pragma unroll
        for (int t16 = 0; t16 < 4; ++t16) {
            #pragma unroll
            for (int r = 0; r < 4; ++r) {
                float p = exp2f(sv[t16][r] - m[r]);
                psum[r] += p;
                Ps[w][l4 * 4 + r][t16 * 16 + l16] = f2bf(p);
            }
        }
        #pragma unroll
        for (int off = 1; off < 16; off <<= 1) {
            #pragma unroll
            for (int r = 0; r < 4; ++r) psum[r] += __shfl_xor(psum[r], off);
        }
        #pragma unroll
        for (int r = 0; r < 4; ++r) l[r] += psum[r];
        // PV (Ps wave-private)
        #pragma unroll
        for (int c = 0; c < 2; ++c) {
            s16x8 pf = *reinterpret_cast<const s16x8*>(&Ps[w][l16][c * 32 + l4 * 8]);
            #pragma unroll
            for (int n16 = 0; n16 < 16; ++n16) {
                int n = n16 * 16 + l16;
                s16x8 vf = *reinterpret_cast<const s16x8*>(VsB + n * 128 + ((c * 64 + l4 * 16) ^ ((n & 7) << 4)));
                o[n16] = __builtin_amdgcn_mfma_f32_16x16x32_bf16(pf, vf, o[n16], 0, 0, 0);
            }
        }
    }
    if (ti < 4) {
        float invl[4];
        #pragma unroll
        for (int r = 0; r < 4; ++r) invl[r] = 1.f / l[r];
        #pragma unroll
        for (int n16 = 0; n16 < 16; ++n16) {
            #pragma unroll
            for (int r = 0; r < 4; ++r) {
                aob[((size_t)b * LL + i0 + w * 16 + l4 * 4 + r) * DVN + n16 * 16 + l16] = f2bf(o[n16][r] * invl[r]);
            }
        }
    } else {
        const size_t slot = (size_t)b * NCHK + cid;
        __hip_bfloat16* po = part_o + slot * (64 * 256);
        #pragma unroll
        for (int n16 = 0; n16 < 16; ++n16) {
            #pragma unroll
            for (int r = 0; r < 4; ++r)
                po[(size_t)(w * 16 + l4 * 4 + r) * 256 + n16 * 16 + l16] = f2bf(o[n16][r]);
        }
        if (l16 == 0) {
            #pragma unroll
            for (int r = 0; r < 4; ++r) {
                int row = w * 16 + l4 * 4 + r;
                part_ml[slot * 128 + row * 2]     = m[r];
                part_ml[slot * 128 + row * 2 + 1] = l[r];
            }
        }
    }
}

// ---------------- combine partials (ti >= 4), nc = ti/4+1 in [2,8], col-half split
__global__ __launch_bounds__(256) void attn_combine(const __hip_bfloat16* __restrict__ part_o,
                                                    const float* __restrict__ part_ml,
                                                    __hip_bfloat16* __restrict__ aob) {
    const int ti = 4 + (int)blockIdx.x;   // 4..31
    const int ch = blockIdx.y;            // column half
    const int b = blockIdx.z;
    const int g = ti >> 2;
    const int nc = g + 1;
    const int cid0 = 2*g*(g+1) + (ti - 4*g)*(g+1);
    const size_t slot0 = (size_t)b * NCHK + cid0;
    __shared__ float sW[8][64];
    __shared__ float sinvL[64];
    const int t = threadIdx.x;
    if (t < 64) {
        float M = -1e30f;
        for (int c = 0; c < nc; ++c)
            M = fmaxf(M, part_ml[(slot0 + c) * 128 + t * 2]);
        float L = 0.f;
        for (int c = 0; c < nc; ++c) {
            float wv = exp2f(part_ml[(slot0 + c) * 128 + t * 2] - M);
            sW[c][t] = wv;
            L += wv * part_ml[(slot0 + c) * 128 + t * 2 + 1];
        }
        sinvL[t] = 1.f / L;
    }
    __syncthreads();
    const int i0 = ti * 64;
    #pragma unroll
    for (int it = 0; it < 4; ++it) {
        int idx = it * 256 + t;           // 8-bf16 units over 64 x 128
        int row = idx >> 4, c8 = idx & 15;
        int colu = ch * 16 + c8;          // unit of 8 cols within 256
        float acc[8] = {0.f,0.f,0.f,0.f,0.f,0.f,0.f,0.f};
        for (int c = 0; c < nc; ++c) {
            float wv = sW[c][row];
            uint4 d = *reinterpret_cast<const uint4*>(part_o + (slot0 + c) * (size_t)(64*256) + row * 256 + colu * 8);
            const ushort* pp = (const ushort*)&d;
            #pragma unroll
            for (int j = 0; j < 8; ++j) acc[j] = fmaf(wv, bf2f(pp[j]), acc[j]);
        }
        float il = sinvL[row];
        ushort pk[8];
        #pragma unroll
        for (int j = 0; j < 8; ++j) pk[j] = f2bfu(acc[j] * il);
        *reinterpret_cast<uint4*>(aob + ((size_t)b * LL + i0 + row) * DVN + colu * 8) = *reinterpret_cast<uint4*>(pk);
    }
}

// ---------------- fused final, split by column half (grid.y)
__global__ __launch_bounds__(256) void final_mfma(
        const __hip_bfloat16* __restrict__ emab, const __hip_bfloat16* __restrict__ aob,
        const __hip_bfloat16* __restrict__ rstb, const float* __restrict__ x,
        const __hip_bfloat16* __restrict__ WhP, const __hip_bfloat16* __restrict__ UhP,
        const __hip_bfloat16* __restrict__ WuP, const float* __restrict__ bh,
        const float* __restrict__ bu, float* __restrict__ out) {
    __shared__ char As1[64*256];   // ema tile, K=128
    __shared__ char As2[64*512];   // gated tile, K=256
    const int row0 = blockIdx.x * 64;
    const int ch = blockIdx.y;     // cols [ch*64, ch*64+64)
    const int t = threadIdx.x, w = t>>6, lane = t&63, l16 = lane&15, l4 = lane>>4;
    #pragma unroll
    for (int p = 0; p < 4; ++p) {
        int idx = p*256 + t;
        int row = idx / 16, u = idx % 16;
        uint4 d = *reinterpret_cast<const uint4*>(emab + (size_t)(row0+row)*DD + u*8);
        *reinterpret_cast<uint4*>(As1 + row*256 + ((u*16) ^ ((row&7)<<4))) = d;
    }
    #pragma unroll
    for (int p = 0; p < 8; ++p) {
        int idx = p*256 + t;
        int row = idx / 32, u = idx % 32;
        uint4 da = *reinterpret_cast<const uint4*>(aob + (size_t)(row0+row)*DVN + u*8);
        uint4 dr = *reinterpret_cast<const uint4*>(rstb + (size_t)(row0+row)*DVN + u*8);
        const ushort* pa = (const ushort*)&da;
        const ushort* pr = (const ushort*)&dr;
        ushort gg[8];
        #pragma unroll
        for (int j = 0; j < 8; ++j) gg[j] = f2bfu(bf2f(pa[j]) * bf2f(pr[j]));
        *reinterpret_cast<uint4*>(As2 + row*512 + ((u*16) ^ ((row&7)<<4))) = *reinterpret_cast<uint4*>(gg);
    }
    __syncthreads();
    f32x4 acc1[4], acc2[4];
    #pragma unroll
    for (int n = 0; n < 4; ++n) { acc1[n] = (f32x4){0.f,0.f,0.f,0.f}; acc2[n] = (f32x4){0.f,0.f,0.f,0.f}; }
    const int arow = w*16 + l16;
    #pragma unroll
    for (int k32 = 0; k32 < 4; ++k32) {
        s16x8 af = *reinterpret_cast<const s16x8*>(As1 + arow*256 + ((k32*64 + l4*16) ^ ((arow&7)<<4)));
        #pragma unroll
        for (int n = 0; n < 4; ++n) {
            s16x8 bw = *reinterpret_cast<const s16x8*>(WhP + ((size_t)((ch*4+n)*4 + k32)*64 + lane)*8);
            acc1[n] = __builtin_amdgcn_mfma_f32_16x16x32_bf16(af, bw, acc1[n], 0, 0, 0);
            s16x8 bu2 = *reinterpret_cast<const s16x8*>(WuP + ((size_t)((ch*4+n)*4 + k32)*64 + lane)*8);
            acc2[n] = __builtin_amdgcn_mfma_f32_16x16x32_bf16(af, bu2, acc2[n], 0, 0, 0);
        }
    }
    #pragma unroll
    for (int k32 = 0; k32 < 8; ++k32) {
        s16x8 gf = *reinterpret_cast<const s16x8*>(As2 + arow*512 + ((k32*64 + l4*16) ^ ((arow&7)<<4)));
        #pragma unroll
        for (int n = 0; n < 4; ++n) {
            s16x8 bw = *reinterpret_cast<const s16x8*>(UhP + ((size_t)((ch*4+n)*8 + k32)*64 + lane)*8);
            acc1[n] = __builtin_amdgcn_mfma_f32_16x16x32_bf16(gf, bw, acc1[n], 0, 0, 0);
        }
    }
    #pragma unroll
    for (int n = 0; n < 4; ++n) {
        int col = ch*64 + n*16 + l16;
        float bbh = bh[col], bbu = bu[col];
        #pragma unroll
        for (int r = 0; r < 4; ++r) {
            int row = w*16 + l4*4 + r;
            size_t gidx = (size_t)(row0+row)*DD + col;
            float hh = siluf_(acc1[n][r] + bbh);
            float u = sigmoidf_(acc2[n][r] + bbu);
            float xv = x[gidx];
            out[gidx] = u*hh + (1.f-u)*xv;
        }
    }
}

extern "C" void kernel_launch(void* const* d_in, const int* in_sizes, int n_in,
                              void* d_out, int out_size, void* d_ws, size_t ws_size,
                              hipStream_t stream) {
    const float* x        = (const float*)d_in[0];
    const float* expansion= (const float*)d_in[1];
    const float* reduction= (const float*)d_in[2];
    const float* alphas   = (const float*)d_in[3];
    const float* damps    = (const float*)d_in[4];
    const float* rel_bias = (const float*)d_in[5];
    const float* W_qk     = (const float*)d_in[6];
    const float* b_qk     = (const float*)d_in[7];
    const float* gamma    = (const float*)d_in[8];
    const float* beta     = (const float*)d_in[9];
    const float* W_v      = (const float*)d_in[10];
    const float* b_v      = (const float*)d_in[11];
    const float* W_reset  = (const float*)d_in[12];
    const float* b_reset  = (const float*)d_in[13];
    const float* W_update = (const float*)d_in[14];
    const float* b_update = (const float*)d_in[15];
    const float* Wh       = (const float*)d_in[16];
    const float* Uh       = (const float*)d_in[17];
    const float* bh       = (const float*)d_in[18];
    float* out = (float*)d_out;

    char* base = (char*)d_ws;
    __hip_bfloat16* emab = (__hip_bfloat16*)base;  base += (size_t)MTOT * DD * 2;
    __hip_bfloat16* xb   = (__hip_bfloat16*)base;  base += (size_t)MTOT * DD * 2;
    __hip_bfloat16* qb   = (__hip_bfloat16*)base;  base += (size_t)MTOT * DQKN * 2;
    __hip_bfloat16* kb   = (__hip_bfloat16*)base;  base += (size_t)MTOT * DQKN * 2;
    __hip_bfloat16* vT   = (__hip_bfloat16*)base;  base += (size_t)MTOT * DVN * 2;
    __hip_bfloat16* rstb = (__hip_bfloat16*)base;  base += (size_t)MTOT * DVN * 2;
    __hip_bfloat16* aob  = (__hip_bfloat16*)base;  base += (size_t)MTOT * DVN * 2;
    float* btab  = (float*)base;                   base += (size_t)LL * 4;
    float* sl    = (float*)base;                   base += (size_t)BB * NCH * 16 * DD * 4;
    float* carry = (float*)base;                   base += (size_t)BB * NCH * 16 * DD * 4;
    __hip_bfloat16* WqkP = (__hip_bfloat16*)base;  base += (size_t)DD * DQKN * 2;
    __hip_bfloat16* WvP  = (__hip_bfloat16*)base;  base += (size_t)DD * DVN * 2;
    __hip_bfloat16* WrstP= (__hip_bfloat16*)base;  base += (size_t)DD * DVN * 2;
    __hip_bfloat16* WuP  = (__hip_bfloat16*)base;  base += (size_t)DD * DD * 2;
    __hip_bfloat16* WhP  = (__hip_bfloat16*)base;  base += (size_t)DD * DD * 2;
    __hip_bfloat16* UhP  = (__hip_bfloat16*)base;  base += (size_t)DVN * DD * 2;
    __hip_bfloat16* part_o = (__hip_bfloat16*)base; base += (size_t)BB * NCHK * 64 * 256 * 2;
    float* part_ml = (float*)base;                 base += (size_t)BB * NCHK * 128 * 4;

    pack_all<<<273, 64, 0, stream>>>(W_qk, W_v, W_reset, W_update, Wh, Uh, rel_bias,
                                     WqkP, WvP, WrstP, WuP, WhP, UhP, btab);

    ema_scanA<<<BB * NCH * DD / 256, 256, 0, stream>>>(x, alphas, damps, sl);
    ema_scanB<<<BB * 16 * DD / 256, 256, 0, stream>>>(alphas, damps, sl, carry);
    ema_scanC<<<BB * NCH * DD / 256, 256, 0, stream>>>(x, expansion, reduction, alphas, damps, carry, emab, xb);

    gemm_qk<<<MTOT/64, 256, 0, stream>>>(emab, WqkP, b_qk, gamma, beta, qb, kb);
    gemm_vrst<<<dim3(MTOT/64, 2), 256, 0, stream>>>(xb, emab, WvP, WrstP, b_v, b_reset, vT, rstb);

    attn_kernel<<<dim3(NCHK, BB), 256, 0, stream>>>(qb, kb, vT, btab, aob, part_o, part_ml);
    attn_combine<<<dim3(28, 2, BB), 256, 0, stream>>>(part_o, part_ml, aob);

    final_mfma<<<dim3(MTOT/64, 2), 256, 0, stream>>>(emab, aob, rstb, x, WhP, UhP, WuP, bh, b_update, out);
}